// Round 23
// baseline (1657.726 us; speedup 1.0000x reference)
//
#include <hip/hip_runtime.h>
#include <hip/hip_bf16.h>
#include <math.h>

#define B_    128
#define S_    100
#define D_    384
#define QK_   48
#define E_    768
#define LOCAL_ 384
#define NB_   8
#define NTOK_ 100
#define NPTS_ 256
#define M_    (B_*S_)   // 12800

typedef unsigned short ushort;
typedef __attribute__((ext_vector_type(8))) short  bf16x8;
typedef __attribute__((ext_vector_type(8))) unsigned short ushort8v;
typedef __attribute__((ext_vector_type(4))) float  f32x4;

#define MFMA(a,b,c) __builtin_amdgcn_mfma_f32_16x16x32_bf16(a,b,c,0,0,0)

// fast GELU (tanh form): max |diff vs exact erf-GELU| ~3e-4, well under tolerance
static __device__ __forceinline__ float gelu_f(float x) {
    float y = 1.5957691216057308f * (x + 0.044715f * x * x * x);
    float e = __expf(y);
    float t = 1.0f - 2.0f / (e + 1.0f);
    return 0.5f * x * (1.0f + t);
}
static __device__ __forceinline__ ushort f2b(float f) {
    union { float f; unsigned u; } x; x.f = f;
    unsigned r = x.u + 0x7FFFu + ((x.u >> 16) & 1u);
    return (ushort)(r >> 16);
}
static __device__ __forceinline__ float b2f(ushort u) {
    union { unsigned u; float f; } x; x.u = ((unsigned)u) << 16;
    return x.f;
}

// XCD-locality swizzle: group row-panels (by) in chunks of 8 so all col-tiles (bx)
// of one panel land on the same XCD (linear IDs differ by 8*xn => same id mod 8).
// Bijective for any gy; tail gy%8 panels fall back to stride tail (2 XCDs).
static __device__ __forceinline__ void xcd_swz(int xn, int gy, int& bx, int& by) {
    int L = blockIdx.x + xn * blockIdx.y;
    int gmain = (gy & ~7) * xn;
    if (L < gmain) {
        int grp = L / (8 * xn);
        int r = L % (8 * xn);
        bx = r >> 3;
        by = grp * 8 + (r & 7);
    } else {
        int Lp = L - gmain;
        int tail = gy & 7;
        by = (gy & ~7) + (Lp % tail);
        bx = Lp / tail;
    }
}

// ---------------- LayerNorm: fp32 in -> bf16 out ----------------
__global__ __launch_bounds__(256)
void ln_rows(const float* __restrict__ X, const float* __restrict__ w,
             ushort* __restrict__ Y, int nrows)
{
    int row = blockIdx.x * 4 + (threadIdx.x >> 6);
    if (row >= nrows) return;
    int lane = threadIdx.x & 63;
    const float* x = X + (size_t)row * D_;
    float v[6]; float s = 0.f;
    #pragma unroll
    for (int t = 0; t < 6; ++t) { v[t] = x[lane + 64*t]; s += v[t]; }
    #pragma unroll
    for (int off = 32; off; off >>= 1) s += __shfl_xor(s, off);
    float mu = s * (1.f/(float)D_);
    float q = 0.f;
    #pragma unroll
    for (int t = 0; t < 6; ++t) { float d = v[t]-mu; q += d*d; }
    #pragma unroll
    for (int off = 32; off; off >>= 1) q += __shfl_xor(q, off);
    float rs = rsqrtf(q * (1.f/(float)D_) + 1e-5f);
    #pragma unroll
    for (int t = 0; t < 6; ++t)
        Y[(size_t)row*D_ + lane + 64*t] = f2b((v[t]-mu)*rs*w[lane + 64*t]);
}

// ------------- gather emb[q] + LayerNorm -> fp32 h -------------
__global__ __launch_bounds__(256)
void x_init(const int* __restrict__ qtok, const float* __restrict__ emb,
            const float* __restrict__ w, float* __restrict__ Y, int nrows)
{
    int row = blockIdx.x * 4 + (threadIdx.x >> 6);
    if (row >= nrows) return;
    int lane = threadIdx.x & 63;
    const float* x = emb + (size_t)qtok[row] * D_;
    float v[6]; float s = 0.f;
    #pragma unroll
    for (int t = 0; t < 6; ++t) { v[t] = x[lane + 64*t]; s += v[t]; }
    #pragma unroll
    for (int off = 32; off; off >>= 1) s += __shfl_xor(s, off);
    float mu = s * (1.f/(float)D_);
    float q = 0.f;
    #pragma unroll
    for (int t = 0; t < 6; ++t) { float d = v[t]-mu; q += d*d; }
    #pragma unroll
    for (int off = 32; off; off >>= 1) q += __shfl_xor(q, off);
    float rs = rsqrtf(q * (1.f/(float)D_) + 1e-5f);
    float* y = Y + (size_t)row * D_;
    #pragma unroll
    for (int t = 0; t < 6; ++t) y[lane + 64*t] = (v[t]-mu)*rs*w[lane + 64*t];
}

// ------------- weight conversion -------------
#define WE_SZ  (1632*384)
#define P1_SZ  (384*768)
#define WQ_SZ  (816*384)
#define P2_SZ  (384*768)
#define WTOT   (WE_SZ + P1_SZ + WQ_SZ + P2_SZ)

static __device__ __forceinline__ void wsplit(float v, ushort* wh, ushort* wl, size_t o) {
    ushort h = f2b(v);
    wh[o] = h; wl[o] = f2b(v - b2f(h));
}

// all layers at once, hi only (plain bf16 weights): blockIdx.y = layer
__global__ __launch_bounds__(256)
void wconv_all_hi(const float* __restrict__ expand, const float* __restrict__ proj1,
                  const float* __restrict__ wq, const float* __restrict__ proj2,
                  ushort* __restrict__ wh)
{
    int i = blockIdx.x*256 + threadIdx.x;
    if (i >= WTOT) return;
    int blk = blockIdx.y;
    float v;
    if (i < WE_SZ) v = expand[(size_t)blk*WE_SZ + i];
    else if (i < WE_SZ+P1_SZ) v = proj1[(size_t)blk*P1_SZ + (i - WE_SZ)];
    else if (i < WE_SZ+P1_SZ+WQ_SZ) v = wq[(size_t)blk*WQ_SZ + (i - WE_SZ - P1_SZ)];
    else v = proj2[(size_t)blk*P2_SZ + (i - WE_SZ - P1_SZ - WQ_SZ)];
    wh[(size_t)blk*WTOT + i] = f2b(v);
}

__global__ __launch_bounds__(256)
void wconv_hi(const float* __restrict__ we, const float* __restrict__ p1,
              const float* __restrict__ wq, const float* __restrict__ p2,
              ushort* __restrict__ wh)
{
    int i = blockIdx.x*256 + threadIdx.x;
    if (i >= WTOT) return;
    float v;
    if (i < WE_SZ) v = we[i];
    else if (i < WE_SZ+P1_SZ) v = p1[i - WE_SZ];
    else if (i < WE_SZ+P1_SZ+WQ_SZ) v = wq[i - WE_SZ - P1_SZ];
    else v = p2[i - WE_SZ - P1_SZ - WQ_SZ];
    wh[i] = f2b(v);
}

__global__ __launch_bounds__(256)
void wconv1(const float* __restrict__ src, int n,
            ushort* __restrict__ wh, ushort* __restrict__ wl)
{
    int i = blockIdx.x*256 + threadIdx.x;
    if (i >= n) return;
    wsplit(src[i], wh, wl, i);
}

// ------------- pt_emb -> bf16, padded to 128 rows -------------
__global__ __launch_bounds__(256)
void pconv(const float* __restrict__ src, ushort* __restrict__ dst)
{
    int i = blockIdx.x*256 + threadIdx.x;
    if (i >= 128*192) return;
    int r = i / 192;
    dst[i] = (r < NTOK_) ? f2b(src[i]) : 0;
}

// ------------- MFMA 2-product GEMM, 64x64 block (final out GEMM, accuracy-critical) -------------
__global__ __launch_bounds__(256)
void mm_bt64(const ushort* __restrict__ A1, int lda1, int K1,
             const ushort* __restrict__ A2, int lda2,
             const ushort* __restrict__ Wgh, const ushort* __restrict__ Wgl,
             float* __restrict__ C, int ldc, int N, int K, int accum)
{
    __shared__ ushort Ah[64][72], Wh[64][72], Wl[64][72];
    int tid = threadIdx.x;
    int row0 = blockIdx.y*64, col0 = blockIdx.x*64;
    int srow = tid >> 3;
    int sseg = (tid & 7) * 8;
    int wid = tid >> 6, lane = tid & 63;
    int wr = wid >> 1, wc = wid & 1;
    int fr = lane & 15, fg = lane >> 4;
    f32x4 acc[2][2] = {};
    for (int k0 = 0; k0 < K; k0 += 64) {
        ushort8v va[2], vc[2], vd[2];
        #pragma unroll
        for (int p = 0; p < 2; ++p) {
            int r = p*32 + srow;
            int arow = row0 + r;
            int wrow = col0 + r;
            int gk = k0 + sseg;
            if (gk < K1) va[p] = *(const ushort8v*)(A1 + (size_t)arow*lda1 + gk);
            else         va[p] = *(const ushort8v*)(A2 + (size_t)arow*lda2 + (gk-K1));
            if (wrow >= N) wrow = N - 1;
            vc[p] = *(const ushort8v*)(Wgh + (size_t)wrow*K + gk);
            vd[p] = *(const ushort8v*)(Wgl + (size_t)wrow*K + gk);
        }
        __syncthreads();
        #pragma unroll
        for (int p = 0; p < 2; ++p) {
            int r = p*32 + srow;
            *(ushort8v*)&Ah[r][sseg] = va[p];
            *(ushort8v*)&Wh[r][sseg] = vc[p];
            *(ushort8v*)&Wl[r][sseg] = vd[p];
        }
        __syncthreads();
        #pragma unroll
        for (int kk = 0; kk < 64; kk += 32) {
            bf16x8 a[2], b_h[2], b_l[2];
            #pragma unroll
            for (int s = 0; s < 2; ++s) {
                a[s]   = *(const bf16x8*)&Ah[wr*32 + s*16 + fr][kk + fg*8];
                b_h[s] = *(const bf16x8*)&Wh[wc*32 + s*16 + fr][kk + fg*8];
                b_l[s] = *(const bf16x8*)&Wl[wc*32 + s*16 + fr][kk + fg*8];
            }
            #pragma unroll
            for (int s = 0; s < 2; ++s)
                #pragma unroll
                for (int u = 0; u < 2; ++u)
                    acc[s][u] = MFMA(a[s], b_h[u], acc[s][u]);
            #pragma unroll
            for (int s = 0; s < 2; ++s)
                #pragma unroll
                for (int u = 0; u < 2; ++u)
                    acc[s][u] = MFMA(a[s], b_l[u], acc[s][u]);
        }
        __syncthreads();
    }
    #pragma unroll
    for (int s = 0; s < 2; ++s) {
        int r = row0 + wr*32 + s*16 + fg*4;
        #pragma unroll
        for (int u = 0; u < 2; ++u) {
            int c = col0 + wc*32 + u*16 + fr;
            if (c < N) {
                #pragma unroll
                for (int j = 0; j < 4; ++j) {
                    size_t o = (size_t)(r+j)*ldc + c;
                    C[o] = accum ? (C[o] + acc[s][u][j]) : acc[s][u][j];
                }
            }
        }
    }
}

// ------------- MFMA single-product GEMM, 128x64 block, wave 64x32 (proj GEMMs), T14 pipelined -------------
__global__ __launch_bounds__(256)
void mm_bt2(const ushort* __restrict__ A1, int lda1, int K1,
            const ushort* __restrict__ A2, int lda2,
            const ushort* __restrict__ Wgh,
            float* __restrict__ C, int ldc, int N, int K, int accum)
{
    __shared__ ushort As[128*32], Whs[64*32];
    int tid = threadIdx.x;
    int lane = tid & 63, wid = tid >> 6;
    int bx, by; xcd_swz(gridDim.x, gridDim.y, bx, by);
    int row0 = by*128, col0 = bx*64;
    int wr = wid >> 1, wc = wid & 1;
    int fr = lane & 15, fg = lane >> 4;
    int gsl = (fg ^ ((fr >> 1) & 3)) * 8;
    int sr = tid >> 2, sg0 = tid & 3;
    int g = sg0 ^ ((sr >> 1) & 3);
    int wrow = col0 + sr; if (wrow >= N) wrow = N - 1;

    ushort8v va[2], vh;
    auto loadk = [&](int k0) {
        const ushort* Asrc; int lda, kk;
        if (k0 < K1) { Asrc = A1; lda = lda1; kk = k0; }
        else         { Asrc = A2; lda = lda2; kk = k0 - K1; }
        #pragma unroll
        for (int i = 0; i < 2; ++i)
            va[i] = *(const ushort8v*)(Asrc + (size_t)(row0 + sr + i*64)*lda + kk + g*8);
        vh = *(const ushort8v*)(Wgh + (size_t)wrow*K + k0 + g*8);
    };

    f32x4 acc[4][2] = {};
    loadk(0);
    for (int k0 = 0; k0 < K; k0 += 32) {
        __syncthreads();
        #pragma unroll
        for (int i = 0; i < 2; ++i)
            *(ushort8v*)&As[(sr + i*64)*32 + sg0*8] = va[i];
        *(ushort8v*)&Whs[sr*32 + sg0*8] = vh;
        if (k0 + 32 < K) loadk(k0 + 32);
        __syncthreads();
        bf16x8 a[4], bh[2];
        #pragma unroll
        for (int s = 0; s < 4; ++s) {
            int r = wr*64 + s*16 + fr;
            a[s] = *(const bf16x8*)&As[r*32 + gsl];
        }
        #pragma unroll
        for (int u = 0; u < 2; ++u) {
            int r = wc*32 + u*16 + fr;
            bh[u] = *(const bf16x8*)&Whs[r*32 + gsl];
        }
        #pragma unroll
        for (int s = 0; s < 4; ++s)
            #pragma unroll
            for (int u = 0; u < 2; ++u)
                acc[s][u] = MFMA(a[s], bh[u], acc[s][u]);
    }
    #pragma unroll
    for (int s = 0; s < 4; ++s) {
        int rb = row0 + wr*64 + s*16 + fg*4;
        #pragma unroll
        for (int u = 0; u < 2; ++u) {
            int c = col0 + wc*32 + u*16 + fr;
            if (c < N) {
                #pragma unroll
                for (int j = 0; j < 4; ++j) {
                    size_t o = (size_t)(rb+j)*ldc + c;
                    C[o] = accum ? (C[o] + acc[s][u][j]) : acc[s][u][j];
                }
            }
        }
    }
}

// ------------- Fused expand GEMM, single-product: bx<nqt -> q GEMM (fp32 out), else GEGLU tile -------------
__global__ __launch_bounds__(256)
void mm_fused2(const ushort* __restrict__ Ag, int lda,
               const ushort* __restrict__ Wqh,
               int Nq, int nqt, float* __restrict__ Qout, int ldq,
               const ushort* __restrict__ W1h, const ushort* __restrict__ W2h,
               ushort* __restrict__ Oh, int ldo, int K)
{
    __shared__ ushort As[128*32];
    __shared__ ushort Xs[2][64*32];
    int tid = threadIdx.x;
    int lane = tid & 63, wid = tid >> 6;
    int bx, by; xcd_swz(gridDim.x, gridDim.y, bx, by);
    int row0 = by*128;
    int wr = wid >> 1, wc = wid & 1;
    int fr = lane & 15, fg = lane >> 4;
    int gsl = (fg ^ ((fr >> 1) & 3)) * 8;
    int sr = tid >> 2, sg0 = tid & 3;
    int g = sg0 ^ ((sr >> 1) & 3);

    if (bx < nqt) {
        int col0 = bx*64;
        int wrow = col0 + sr; if (wrow >= Nq) wrow = Nq - 1;
        ushort8v va[2], vh;
        auto loadk = [&](int k0) {
            #pragma unroll
            for (int i = 0; i < 2; ++i)
                va[i] = *(const ushort8v*)(Ag + (size_t)(row0 + sr + i*64)*lda + k0 + g*8);
            vh = *(const ushort8v*)(Wqh + (size_t)wrow*K + k0 + g*8);
        };
        f32x4 acc[4][2] = {};
        loadk(0);
        for (int k0 = 0; k0 < K; k0 += 32) {
            __syncthreads();
            #pragma unroll
            for (int i = 0; i < 2; ++i)
                *(ushort8v*)&As[(sr + i*64)*32 + sg0*8] = va[i];
            *(ushort8v*)&Xs[0][sr*32 + sg0*8] = vh;
            if (k0 + 32 < K) loadk(k0 + 32);
            __syncthreads();
            bf16x8 a[4], bh[2];
            #pragma unroll
            for (int s = 0; s < 4; ++s) {
                int r = wr*64 + s*16 + fr;
                a[s] = *(const bf16x8*)&As[r*32 + gsl];
            }
            #pragma unroll
            for (int u = 0; u < 2; ++u) {
                int r = wc*32 + u*16 + fr;
                bh[u] = *(const bf16x8*)&Xs[0][r*32 + gsl];
            }
            #pragma unroll
            for (int s = 0; s < 4; ++s)
                #pragma unroll
                for (int u = 0; u < 2; ++u)
                    acc[s][u] = MFMA(a[s], bh[u], acc[s][u]);
        }
        #pragma unroll
        for (int s = 0; s < 4; ++s) {
            int rb = row0 + wr*64 + s*16 + fg*4;
            #pragma unroll
            for (int u = 0; u < 2; ++u) {
                int c = col0 + wc*32 + u*16 + fr;
                if (c < Nq) {
                    #pragma unroll
                    for (int j = 0; j < 4; ++j)
                        Qout[(size_t)(rb+j)*ldq + c] = acc[s][u][j];
                }
            }
        }
    } else {
        int col0 = (bx - nqt)*64;
        ushort8v va[2], vw0, vw2;
        auto loadk = [&](int k0) {
            #pragma unroll
            for (int i = 0; i < 2; ++i)
                va[i] = *(const ushort8v*)(Ag + (size_t)(row0 + sr + i*64)*lda + k0 + g*8);
            size_t wro = (size_t)(col0 + sr)*K + k0 + g*8;
            vw0 = *(const ushort8v*)(W1h + wro);
            vw2 = *(const ushort8v*)(W2h + wro);
        };
        f32x4 acc1[4][2] = {}, acc2[4][2] = {};
        loadk(0);
        for (int k0 = 0; k0 < K; k0 += 32) {
            __syncthreads();
            #pragma unroll
            for (int i = 0; i < 2; ++i)
                *(ushort8v*)&As[(sr + i*64)*32 + sg0*8] = va[i];
            {
                int o = sr*32 + sg0*8;
                *(ushort8v*)&Xs[0][o] = vw0;
                *(ushort8v*)&Xs[1][o] = vw2;
            }
            if (k0 + 32 < K) loadk(k0 + 32);
            __syncthreads();
            bf16x8 a[4], b1[2], b2[2];
            #pragma unroll
            for (int s = 0; s < 4; ++s) {
                int r = wr*64 + s*16 + fr;
                a[s] = *(const bf16x8*)&As[r*32 + gsl];
            }
            #pragma unroll
            for (int u = 0; u < 2; ++u) {
                int r = wc*32 + u*16 + fr;
                b1[u] = *(const bf16x8*)&Xs[0][r*32 + gsl];
                b2[u] = *(const bf16x8*)&Xs[1][r*32 + gsl];
            }
            #pragma unroll
            for (int s = 0; s < 4; ++s)
                #pragma unroll
                for (int u = 0; u < 2; ++u) {
                    acc1[s][u] = MFMA(a[s], b1[u], acc1[s][u]);
                    acc2[s][u] = MFMA(a[s], b2[u], acc2[s][u]);
                }
        }
        #pragma unroll
        for (int s = 0; s < 4; ++s) {
            int rb = row0 + wr*64 + s*16 + fg*4;
            #pragma unroll
            for (int u = 0; u < 2; ++u) {
                int c = col0 + wc*32 + u*16 + fr;
                #pragma unroll
                for (int j = 0; j < 4; ++j) {
                    float gg = acc1[s][u][j] * gelu_f(acc2[s][u][j]);
                    Oh[(size_t)(rb+j)*ldo + c] = f2b(gg);
                }
            }
        }
    }
}

// ------------- batched pk GEMM (2-product, precomputed once): P12[z] = ptp @ Wkv[z]^T -------------
__global__ __launch_bounds__(256)
void pk_mm(const ushort* __restrict__ A,
           const ushort* __restrict__ Wh_, const ushort* __restrict__ Wl_,
           float* __restrict__ P12)
{
    __shared__ ushort Ah[64][72], Wh[64][72], Wl[64][72];
    int tid = threadIdx.x;
    int z = blockIdx.z, blk = z >> 1, half = z & 1;
    int row0 = blockIdx.y*64, col0 = blockIdx.x*64;
    int srow = tid >> 3, sseg = (tid & 7) * 8;
    int wid = tid >> 6, lane = tid & 63;
    int wr = wid >> 1, wc = wid & 1;
    int fr = lane & 15, fg = lane >> 4;
    const ushort* Wbh = Wh_ + (size_t)blk*816*384 + half*192;
    const ushort* Wbl = Wl_ + (size_t)blk*816*384 + half*192;
    float* C = P12 + (size_t)z*128*816;
    f32x4 acc[2][2] = {};
    for (int k0 = 0; k0 < 192; k0 += 64) {
        ushort8v va[2], vc[2], vd[2];
        #pragma unroll
        for (int p = 0; p < 2; ++p) {
            int r = p*32 + srow;
            int wrow = col0 + r; if (wrow >= 816) wrow = 815;
            int gk = k0 + sseg;
            va[p] = *(const ushort8v*)(A + (size_t)(row0 + r)*192 + gk);
            vc[p] = *(const ushort8v*)(Wbh + (size_t)wrow*384 + gk);
            vd[p] = *(const ushort8v*)(Wbl + (size_t)wrow*384 + gk);
        }
        __syncthreads();
        #pragma unroll
        for (int p = 0; p < 2; ++p) {
            int r = p*32 + srow;
            *(ushort8v*)&Ah[r][sseg] = va[p];
            *(ushort8v*)&Wh[r][sseg] = vc[p];
            *(ushort8v*)&Wl[r][sseg] = vd[p];
        }
        __syncthreads();
        #pragma unroll
        for (int kk = 0; kk < 64; kk += 32) {
            bf16x8 a[2], b_h[2], b_l[2];
            #pragma unroll
            for (int s = 0; s < 2; ++s) {
                a[s]   = *(const bf16x8*)&Ah[wr*32 + s*16 + fr][kk + fg*8];
                b_h[s] = *(const bf16x8*)&Wh[wc*32 + s*16 + fr][kk + fg*8];
                b_l[s] = *(const bf16x8*)&Wl[wc*32 + s*16 + fr][kk + fg*8];
            }
            #pragma unroll
            for (int s = 0; s < 2; ++s)
                #pragma unroll
                for (int u = 0; u < 2; ++u)
                    acc[s][u] = MFMA(a[s], b_h[u], acc[s][u]);
            #pragma unroll
            for (int s = 0; s < 2; ++s)
                #pragma unroll
                for (int u = 0; u < 2; ++u)
                    acc[s][u] = MFMA(a[s], b_l[u], acc[s][u]);
        }
        __syncthreads();
    }
    #pragma unroll
    for (int s = 0; s < 2; ++s) {
        int r = row0 + wr*32 + s*16 + fg*4;
        #pragma unroll
        for (int u = 0; u < 2; ++u) {
            int c = col0 + wc*32 + u*16 + fr;
            if (c < 816) {
                #pragma unroll
                for (int j = 0; j < 4; ++j)
                    C[(size_t)(r+j)*816 + c] = acc[s][u][j];
            }
        }
    }
}

// ------------- MFMA batched PV v2: 64x128 block, wave 64x32, T14 pipelined -------------
// XCD swizzle: all blocks of one batch (same z) share V/P panels -> same XCD.
__global__ __launch_bounds__(256)
void pv2(const ushort* __restrict__ P, int ldp, long sP,
         const ushort* __restrict__ V, int ldv, long sV,
         ushort* __restrict__ Oh, int ldo, long sO,
         int Mrows, int K, int Kv)
{
    __shared__ ushort Ps[64][40];
    __shared__ ushort Vs[128*32];
    int L = blockIdx.x + gridDim.x*(blockIdx.y + gridDim.y*blockIdx.z);
    int gz = gridDim.z;
    int zz = L % gz;                    // gz=128 (multiple of 8) -> same zz => same XCD
    int rest = L / gz;
    int bx = rest % gridDim.x;
    int byy = rest / gridDim.x;
    const ushort* Pb = P + (size_t)zz * sP;
    const ushort* Vb = V + (size_t)zz * sV;
    ushort* Ohb = Oh + (size_t)zz * sO;
    int tid = threadIdx.x;
    int row0 = byy*64, col0 = bx*128;
    int wid = tid >> 6, lane = tid & 63;
    int fr = lane & 15, fg = lane >> 4;
    int prow = tid >> 2, pseg = (tid & 3) * 8;
    int vk = tid & 31, vcb = (tid >> 5) * 8;

    ushort8v pv_, vv[2];
    auto loadk = [&](int k0) {
        pv_ = (ushort8v){0,0,0,0,0,0,0,0};
        int grow = row0 + prow;
        if (grow < Mrows)
            pv_ = *(const ushort8v*)(Pb + (size_t)grow*ldp + k0 + pseg);
        vv[0] = (ushort8v){0,0,0,0,0,0,0,0};
        vv[1] = (ushort8v){0,0,0,0,0,0,0,0};
        int gk = k0 + vk;
        if (gk < Kv) {
            #pragma unroll
            for (int i = 0; i < 2; ++i)
                vv[i] = *(const ushort8v*)(Vb + (size_t)gk*ldv + col0 + vcb + i*64);
        }
    };

    f32x4 acc[4][2] = {};
    loadk(0);
    for (int k0 = 0; k0 < K; k0 += 32) {
        __syncthreads();
        *(ushort8v*)&Ps[prow][pseg] = pv_;
        #pragma unroll
        for (int i = 0; i < 2; ++i) {
            #pragma unroll
            for (int e = 0; e < 8; ++e) {
                int c = vcb + i*64 + e;
                Vs[c*32 + (vk & 7) + 8*((vk >> 3) ^ ((c >> 3) & 3))] = vv[i][e];
            }
        }
        if (k0 + 32 < K) loadk(k0 + 32);
        __syncthreads();
        bf16x8 a[4], b[2];
        #pragma unroll
        for (int s = 0; s < 4; ++s)
            a[s] = *(const bf16x8*)&Ps[s*16 + fr][fg*8];
        #pragma unroll
        for (int u = 0; u < 2; ++u) {
            int c = wid*32 + u*16 + fr;
            b[u] = *(const bf16x8*)&Vs[c*32 + 8*(fg ^ ((c >> 3) & 3))];
        }
        #pragma unroll
        for (int s = 0; s < 4; ++s)
            #pragma unroll
            for (int u = 0; u < 2; ++u)
                acc[s][u] = MFMA(a[s], b[u], acc[s][u]);
    }
    #pragma unroll
    for (int s = 0; s < 4; ++s) {
        int rbase = row0 + s*16 + fg*4;
        #pragma unroll
        for (int u = 0; u < 2; ++u) {
            int c = col0 + wid*32 + u*16 + fr;
            #pragma unroll
            for (int j = 0; j < 4; ++j) {
                int r = rbase + j;
                if (r < Mrows)
                    Ohb[(size_t)r*ldo + c] = f2b(acc[s][u][j]);
            }
        }
    }
}

// ------------- attention 1 scores -> normalized P (bf16) -------------
__global__ __launch_bounds__(256)
void attn1_score(const float* __restrict__ qk, const float* __restrict__ bm, int blk,
                 ushort* __restrict__ P)
{
    __shared__ float qrs[50][QK_];
    __shared__ float krs[S_][QK_+1];
    int b = blockIdx.x, r0 = blockIdx.y*50;
    int tid = threadIdx.x;
    for (int idx = tid; idx < 50*QK_; idx += 256) {
        int r = idx / QK_, c = idx % QK_;
        qrs[r][c] = qk[((size_t)(b*S_ + r0 + r))*96 + c];
    }
    for (int idx = tid; idx < S_*QK_; idx += 256) {
        int r = idx / QK_, c = idx % QK_;
        krs[r][c] = qk[((size_t)(b*S_ + r))*96 + 48 + c];
    }
    __syncthreads();
    float bmv = bm[blk];
    float sp = (bmv > 20.f) ? bmv : log1pf(expf(bmv));
    const float scale = 0.14433756729740643f;
    int w = tid >> 6, lane = tid & 63;
    for (int t = 0; t < 13; ++t) {
        int li = w + 4*t;
        if (li >= 50) break;
        int i = r0 + li;
        int j1 = lane, j2 = lane + 64;
        float s1 = -1e30f, s2 = -1e30f;
        if (j1 <= i) {
            float acc = 0.f;
            #pragma unroll
            for (int l = 0; l < QK_; ++l) acc += qrs[li][l]*krs[j1][l];
            s1 = acc*scale + sp*(float)(j1 - i);
        }
        if (j2 <= i) {
            float acc = 0.f;
            #pragma unroll
            for (int l = 0; l < QK_; ++l) acc += qrs[li][l]*krs[j2][l];
            s2 = acc*scale + sp*(float)(j2 - i);
        }
        float m = fmaxf(s1, s2);
        #pragma unroll
        for (int off = 32; off; off >>= 1) m = fmaxf(m, __shfl_xor(m, off));
        float p1 = (j1 <= i) ? expf(s1 - m) : 0.f;
        float p2 = (j2 <= i) ? expf(s2 - m) : 0.f;
        float sum = p1 + p2;
        #pragma unroll
        for (int off = 32; off; off >>= 1) sum += __shfl_xor(sum, off);
        float inv = 1.f / sum;
        ushort* prow = P + ((size_t)(b*S_) + i)*128;
        prow[j1] = f2b(p1*inv);
        prow[j2] = f2b(p2*inv);
    }
}

// ------------- attention 2 scores -> normalized P (bf16) -------------
__global__ __launch_bounds__(256)
void attn2_score(const float* __restrict__ q2, const float* __restrict__ k2,
                 ushort* __restrict__ P)
{
    __shared__ float ks[NPTS_][QK_+1];
    int b = blockIdx.x, r0 = blockIdx.y*20;
    int tid = threadIdx.x;
    for (int idx = tid; idx < NPTS_*QK_; idx += 256) {
        int r = idx / QK_, c = idx % QK_;
        ks[r][c] = k2[((size_t)(b*NPTS_ + r))*QK_ + c];
    }
    __syncthreads();
    const float scale = 0.14433756729740643f;
    int w = tid >> 6, lane = tid & 63;
    for (int t = 0; t < 5; ++t) {
        int i = r0 + w + 4*t;
        const float* qr = q2 + ((size_t)(b*S_ + i))*QK_;
        float s[4] = {0.f,0.f,0.f,0.f};
        for (int l = 0; l < QK_; ++l) {
            float ql = qr[l];
            #pragma unroll
            for (int r = 0; r < 4; ++r) s[r] += ql * ks[lane + 64*r][l];
        }
        #pragma unroll
        for (int r = 0; r < 4; ++r) s[r] *= scale;
        float m = fmaxf(fmaxf(s[0],s[1]), fmaxf(s[2],s[3]));
        #pragma unroll
        for (int off = 32; off; off >>= 1) m = fmaxf(m, __shfl_xor(m, off));
        float p[4]; float sum = 0.f;
        #pragma unroll
        for (int r = 0; r < 4; ++r) { p[r] = expf(s[r]-m); sum += p[r]; }
        #pragma unroll
        for (int off = 32; off; off >>= 1) sum += __shfl_xor(sum, off);
        float inv = 1.f / sum;
        ushort* prow = P + ((size_t)(b*S_) + i)*256;
        #pragma unroll
        for (int r = 0; r < 4; ++r) prow[lane + 64*r] = f2b(p[r]*inv);
    }
}

// ------------- gather pk rows -> k2 (fp32), geglu'd values gv (bf16) -------------
__global__ __launch_bounds__(256)
void pk_gather(const int* __restrict__ pts, const float* __restrict__ P12, int blk,
               float* __restrict__ k2, ushort* __restrict__ gv)
{
    int pair = blockIdx.x*4 + (threadIdx.x >> 6);
    int lane = threadIdx.x & 63;
    const float* P1 = P12 + (size_t)(blk*2 + 0)*128*816;
    const float* P2 = P12 + (size_t)(blk*2 + 1)*128*816;
    int t0 = pts[2*pair], t1 = pts[2*pair+1];
    const float* a = P1 + (size_t)t0*816;
    const float* c = P2 + (size_t)t1*816;
    if (lane < QK_) k2[(size_t)pair*QK_ + lane] = a[lane] + c[lane];
    #pragma unroll
    for (int t = 0; t < 6; ++t) {
        int i = lane + 64*t;
        float lin = a[48 + i] + c[48 + i];
        float pre = a[432 + i] + c[432 + i];
        gv[(size_t)pair*D_ + i] = f2b(lin * gelu_f(pre));
    }
}

extern "C" void kernel_launch(void* const* d_in, const int* in_sizes, int n_in,
                              void* d_out, int out_size, void* d_ws, size_t ws_size,
                              hipStream_t stream)
{
    const int*   qtok  = (const int*)d_in[0];
    const int*   pts   = (const int*)d_in[1];
    const float* emb   = (const float*)d_in[2];
    const float* ptemb = (const float*)d_in[3];
    const float* normw = (const float*)d_in[4];
    const float* outw  = (const float*)d_in[5];
    const float* ln1   = (const float*)d_in[6];
    const float* expand= (const float*)d_in[7];
    const float* proj1 = (const float*)d_in[8];
    const float* bm    = (const float*)d_in[9];
    const float* ln2   = (const float*)d_in[10];
    const float* Wq    = (const float*)d_in[11];
    const float* Wkv   = (const float*)d_in[12];
    const float* proj2 = (const float*)d_in[13];
    float* out = (float*)d_out;

    char* base = (char*)d_ws;
    size_t off = 0;
    auto alloc = [&](size_t bytes){ void* p = base + off; off += (bytes + 255) & ~(size_t)255; return p; };
    float*  h     = (float*) alloc((size_t)M_*D_*4);
    ushort* nh    = (ushort*)alloc((size_t)M_*D_*2);
    float*  qk1   = (float*) alloc((size_t)M_*96*4);     // qr2 aliases
    ushort* gegl  = (ushort*)alloc((size_t)M_*E_*2);     // gloc aliases
    ushort* atb   = (ushort*)alloc((size_t)M_*D_*2);
    ushort* Pbuf  = (ushort*)alloc((size_t)M_*256*2);
    ushort* gv    = (ushort*)alloc((size_t)B_*NPTS_*D_*2);
    float*  P12   = (float*) alloc((size_t)16*128*816*4);
    float*  k2    = (float*) alloc((size_t)B_*NPTS_*QK_*4);
    ushort* wkvh  = (ushort*)alloc((size_t)NB_*816*384*2);
    ushort* wkvl  = (ushort*)alloc((size_t)NB_*816*384*2);
    ushort* ptp   = (ushort*)alloc((size_t)128*192*2);
    ushort* obh   = (ushort*)alloc((size_t)NTOK_*D_*2);
    ushort* obl   = (ushort*)alloc((size_t)NTOK_*D_*2);

    // weight buffer (hi only): all 8 layers if workspace allows, else single-layer
    size_t rem = (ws_size > off) ? (ws_size - off) : 0;
    bool fits8 = rem >= ((size_t)NB_ * WTOT * 2 + 1024);
    int nlay = fits8 ? NB_ : 1;
    ushort* wbh = (ushort*)alloc((size_t)nlay*WTOT*2);
    size_t wstride = fits8 ? (size_t)WTOT : 0;

    float*  qr2   = qk1;
    ushort* gloc  = gegl;

    const size_t oWE = 0;
    const size_t oP1 = WE_SZ;
    const size_t oWQ = WE_SZ + P1_SZ;
    const size_t oP2 = WE_SZ + P1_SZ + WQ_SZ;

    x_init<<<M_/4, 256, 0, stream>>>(qtok, emb, normw, h, M_);
    pconv<<<(128*192 + 255)/256, 256, 0, stream>>>(ptemb, ptp);
    wconv1<<<(NB_*816*384 + 255)/256, 256, 0, stream>>>(Wkv, NB_*816*384, wkvh, wkvl);
    pk_mm<<<dim3(13, 2, 16), 256, 0, stream>>>(ptp, wkvh, wkvl, P12);
    if (fits8)
        wconv_all_hi<<<dim3((WTOT+255)/256, NB_), 256, 0, stream>>>(
            expand, proj1, Wq, proj2, wbh);

    for (int blk = 0; blk < NB_; ++blk) {
        if (!fits8)
            wconv_hi<<<(WTOT+255)/256, 256, 0, stream>>>(
                expand + (size_t)blk*WE_SZ, proj1 + (size_t)blk*P1_SZ,
                Wq + (size_t)blk*WQ_SZ, proj2 + (size_t)blk*P2_SZ, wbh);
        const ushort* Lh = wbh + wstride*blk;

        ln_rows<<<M_/4, 256, 0, stream>>>(h, ln1 + blk*D_, nh, M_);
        // fused: qk (N=96 -> 2 tiles) + geglu768 (12 tiles)
        mm_fused2<<<dim3(14, M_/128), 256, 0, stream>>>(nh, D_,
            Lh + oWE, 96, 2, qk1, 96,
            Lh + oWE + (size_t)96*D_, Lh + oWE + (size_t)864*D_,
            gegl, E_, D_);
        attn1_score<<<dim3(B_,2), 256, 0, stream>>>(qk1, bm, blk, Pbuf);
        pv2<<<dim3(3,2,B_), 256, 0, stream>>>(Pbuf, 128, (long)S_*128,
            gegl + LOCAL_, E_, (long)S_*E_,
            atb, D_, (long)S_*D_, S_, 128, S_);
        // h += [geglu_local | attn] @ W_p1^T
        mm_bt2<<<dim3(6, M_/128), 256, 0, stream>>>(gegl, E_, D_, atb, D_,
            Lh + oP1, h, D_, D_, E_, 1);

        ln_rows<<<M_/4, 256, 0, stream>>>(h, ln2 + blk*D_, nh, M_);
        // fused: qr2 (N=48 -> 1 tile) + geglu384 (6 tiles)
        mm_fused2<<<dim3(7, M_/128), 256, 0, stream>>>(nh, D_,
            Lh + oWQ, 48, 1, qr2, 48,
            Lh + oWQ + (size_t)48*D_, Lh + oWQ + (size_t)432*D_,
            gloc, D_, D_);
        // pk path (P12 precomputed)
        pk_gather<<<B_*NPTS_/4, 256, 0, stream>>>(pts, P12, blk, k2, gv);
        attn2_score<<<dim3(B_,5), 256, 0, stream>>>(qr2, k2, Pbuf);
        pv2<<<dim3(3,2,B_), 256, 0, stream>>>(Pbuf, 256, (long)S_*256,
            gv, D_, (long)NPTS_*D_,
            atb, D_, (long)S_*D_, S_, 256, 256);
        // h += [g_local | attn2] @ W_p2^T
        mm_bt2<<<dim3(6, M_/128), 256, 0, stream>>>(gloc, D_, D_, atb, D_,
            Lh + oP2, h, D_, D_, E_, 1);
    }

    ln_rows<<<M_/4, 256, 0, stream>>>(h, normw, nh, M_);
    wconv1<<<(NTOK_*D_ + 255)/256, 256, 0, stream>>>(outw, NTOK_*D_, obh, obl);
    mm_bt64<<<dim3(2, M_/64), 256, 0, stream>>>(nh, D_, D_, nh, D_,
        obh, obl, out, NTOK_, NTOK_, D_, 0);
}

// Round 24
// 1649.902 us; speedup vs baseline: 1.0047x; 1.0047x over previous
//
#include <hip/hip_runtime.h>
#include <hip/hip_bf16.h>
#include <math.h>

#define B_    128
#define S_    100
#define D_    384
#define QK_   48
#define E_    768
#define LOCAL_ 384
#define NB_   8
#define NTOK_ 100
#define NPTS_ 256
#define M_    (B_*S_)   // 12800

typedef unsigned short ushort;
typedef __attribute__((ext_vector_type(8))) short  bf16x8;
typedef __attribute__((ext_vector_type(8))) unsigned short ushort8v;
typedef __attribute__((ext_vector_type(4))) float  f32x4;

#define MFMA(a,b,c) __builtin_amdgcn_mfma_f32_16x16x32_bf16(a,b,c,0,0,0)

// fast GELU (tanh form): max |diff vs exact erf-GELU| ~3e-4, well under tolerance
static __device__ __forceinline__ float gelu_f(float x) {
    float y = 1.5957691216057308f * (x + 0.044715f * x * x * x);
    float e = __expf(y);
    float t = 1.0f - 2.0f / (e + 1.0f);
    return 0.5f * x * (1.0f + t);
}
static __device__ __forceinline__ ushort f2b(float f) {
    union { float f; unsigned u; } x; x.f = f;
    unsigned r = x.u + 0x7FFFu + ((x.u >> 16) & 1u);
    return (ushort)(r >> 16);
}
static __device__ __forceinline__ float b2f(ushort u) {
    union { unsigned u; float f; } x; x.u = ((unsigned)u) << 16;
    return x.f;
}

// XCD-locality swizzle: group row-panels (by) in chunks of 8 so all col-tiles (bx)
// of one panel land on the same XCD.
static __device__ __forceinline__ void xcd_swz(int xn, int gy, int& bx, int& by) {
    int L = blockIdx.x + xn * blockIdx.y;
    int gmain = (gy & ~7) * xn;
    if (L < gmain) {
        int grp = L / (8 * xn);
        int r = L % (8 * xn);
        bx = r >> 3;
        by = grp * 8 + (r & 7);
    } else {
        int Lp = L - gmain;
        int tail = gy & 7;
        by = (gy & ~7) + (Lp % tail);
        bx = Lp / tail;
    }
}

// ---------------- LayerNorm: fp32 in -> bf16 out ----------------
__global__ __launch_bounds__(256)
void ln_rows(const float* __restrict__ X, const float* __restrict__ w,
             ushort* __restrict__ Y, int nrows)
{
    int row = blockIdx.x * 4 + (threadIdx.x >> 6);
    if (row >= nrows) return;
    int lane = threadIdx.x & 63;
    const float* x = X + (size_t)row * D_;
    float v[6]; float s = 0.f;
    #pragma unroll
    for (int t = 0; t < 6; ++t) { v[t] = x[lane + 64*t]; s += v[t]; }
    #pragma unroll
    for (int off = 32; off; off >>= 1) s += __shfl_xor(s, off);
    float mu = s * (1.f/(float)D_);
    float q = 0.f;
    #pragma unroll
    for (int t = 0; t < 6; ++t) { float d = v[t]-mu; q += d*d; }
    #pragma unroll
    for (int off = 32; off; off >>= 1) q += __shfl_xor(q, off);
    float rs = rsqrtf(q * (1.f/(float)D_) + 1e-5f);
    #pragma unroll
    for (int t = 0; t < 6; ++t)
        Y[(size_t)row*D_ + lane + 64*t] = f2b((v[t]-mu)*rs*w[lane + 64*t]);
}

// ------------- gather emb[q] + LayerNorm -> fp32 h -------------
__global__ __launch_bounds__(256)
void x_init(const int* __restrict__ qtok, const float* __restrict__ emb,
            const float* __restrict__ w, float* __restrict__ Y, int nrows)
{
    int row = blockIdx.x * 4 + (threadIdx.x >> 6);
    if (row >= nrows) return;
    int lane = threadIdx.x & 63;
    const float* x = emb + (size_t)qtok[row] * D_;
    float v[6]; float s = 0.f;
    #pragma unroll
    for (int t = 0; t < 6; ++t) { v[t] = x[lane + 64*t]; s += v[t]; }
    #pragma unroll
    for (int off = 32; off; off >>= 1) s += __shfl_xor(s, off);
    float mu = s * (1.f/(float)D_);
    float q = 0.f;
    #pragma unroll
    for (int t = 0; t < 6; ++t) { float d = v[t]-mu; q += d*d; }
    #pragma unroll
    for (int off = 32; off; off >>= 1) q += __shfl_xor(q, off);
    float rs = rsqrtf(q * (1.f/(float)D_) + 1e-5f);
    float* y = Y + (size_t)row * D_;
    #pragma unroll
    for (int t = 0; t < 6; ++t) y[lane + 64*t] = (v[t]-mu)*rs*w[lane + 64*t];
}

// ------------- weight conversion -------------
#define WE_SZ  (1632*384)
#define P1_SZ  (384*768)
#define WQ_SZ  (816*384)
#define P2_SZ  (384*768)
#define WTOT   (WE_SZ + P1_SZ + WQ_SZ + P2_SZ)

static __device__ __forceinline__ void wsplit(float v, ushort* wh, ushort* wl, size_t o) {
    ushort h = f2b(v);
    wh[o] = h; wl[o] = f2b(v - b2f(h));
}

// all layers at once, hi only (plain bf16 weights): blockIdx.y = layer
__global__ __launch_bounds__(256)
void wconv_all_hi(const float* __restrict__ expand, const float* __restrict__ proj1,
                  const float* __restrict__ wq, const float* __restrict__ proj2,
                  ushort* __restrict__ wh)
{
    int i = blockIdx.x*256 + threadIdx.x;
    if (i >= WTOT) return;
    int blk = blockIdx.y;
    float v;
    if (i < WE_SZ) v = expand[(size_t)blk*WE_SZ + i];
    else if (i < WE_SZ+P1_SZ) v = proj1[(size_t)blk*P1_SZ + (i - WE_SZ)];
    else if (i < WE_SZ+P1_SZ+WQ_SZ) v = wq[(size_t)blk*WQ_SZ + (i - WE_SZ - P1_SZ)];
    else v = proj2[(size_t)blk*P2_SZ + (i - WE_SZ - P1_SZ - WQ_SZ)];
    wh[(size_t)blk*WTOT + i] = f2b(v);
}

__global__ __launch_bounds__(256)
void wconv_hi(const float* __restrict__ we, const float* __restrict__ p1,
              const float* __restrict__ wq, const float* __restrict__ p2,
              ushort* __restrict__ wh)
{
    int i = blockIdx.x*256 + threadIdx.x;
    if (i >= WTOT) return;
    float v;
    if (i < WE_SZ) v = we[i];
    else if (i < WE_SZ+P1_SZ) v = p1[i - WE_SZ];
    else if (i < WE_SZ+P1_SZ+WQ_SZ) v = wq[i - WE_SZ - P1_SZ];
    else v = p2[i - WE_SZ - P1_SZ - WQ_SZ];
    wh[i] = f2b(v);
}

__global__ __launch_bounds__(256)
void wconv1(const float* __restrict__ src, int n,
            ushort* __restrict__ wh, ushort* __restrict__ wl)
{
    int i = blockIdx.x*256 + threadIdx.x;
    if (i >= n) return;
    wsplit(src[i], wh, wl, i);
}

// ------------- pt_emb -> bf16, padded to 128 rows -------------
__global__ __launch_bounds__(256)
void pconv(const float* __restrict__ src, ushort* __restrict__ dst)
{
    int i = blockIdx.x*256 + threadIdx.x;
    if (i >= 128*192) return;
    int r = i / 192;
    dst[i] = (r < NTOK_) ? f2b(src[i]) : 0;
}

// ------------- MFMA 2-product GEMM, 64x64 block (final out GEMM, accuracy-critical) -------------
__global__ __launch_bounds__(256)
void mm_bt64(const ushort* __restrict__ A1, int lda1, int K1,
             const ushort* __restrict__ A2, int lda2,
             const ushort* __restrict__ Wgh, const ushort* __restrict__ Wgl,
             float* __restrict__ C, int ldc, int N, int K, int accum)
{
    __shared__ ushort Ah[64][72], Wh[64][72], Wl[64][72];
    int tid = threadIdx.x;
    int row0 = blockIdx.y*64, col0 = blockIdx.x*64;
    int srow = tid >> 3;
    int sseg = (tid & 7) * 8;
    int wid = tid >> 6, lane = tid & 63;
    int wr = wid >> 1, wc = wid & 1;
    int fr = lane & 15, fg = lane >> 4;
    f32x4 acc[2][2] = {};
    for (int k0 = 0; k0 < K; k0 += 64) {
        ushort8v va[2], vc[2], vd[2];
        #pragma unroll
        for (int p = 0; p < 2; ++p) {
            int r = p*32 + srow;
            int arow = row0 + r;
            int wrow = col0 + r;
            int gk = k0 + sseg;
            if (gk < K1) va[p] = *(const ushort8v*)(A1 + (size_t)arow*lda1 + gk);
            else         va[p] = *(const ushort8v*)(A2 + (size_t)arow*lda2 + (gk-K1));
            if (wrow >= N) wrow = N - 1;
            vc[p] = *(const ushort8v*)(Wgh + (size_t)wrow*K + gk);
            vd[p] = *(const ushort8v*)(Wgl + (size_t)wrow*K + gk);
        }
        __syncthreads();
        #pragma unroll
        for (int p = 0; p < 2; ++p) {
            int r = p*32 + srow;
            *(ushort8v*)&Ah[r][sseg] = va[p];
            *(ushort8v*)&Wh[r][sseg] = vc[p];
            *(ushort8v*)&Wl[r][sseg] = vd[p];
        }
        __syncthreads();
        #pragma unroll
        for (int kk = 0; kk < 64; kk += 32) {
            bf16x8 a[2], b_h[2], b_l[2];
            #pragma unroll
            for (int s = 0; s < 2; ++s) {
                a[s]   = *(const bf16x8*)&Ah[wr*32 + s*16 + fr][kk + fg*8];
                b_h[s] = *(const bf16x8*)&Wh[wc*32 + s*16 + fr][kk + fg*8];
                b_l[s] = *(const bf16x8*)&Wl[wc*32 + s*16 + fr][kk + fg*8];
            }
            #pragma unroll
            for (int s = 0; s < 2; ++s)
                #pragma unroll
                for (int u = 0; u < 2; ++u)
                    acc[s][u] = MFMA(a[s], b_h[u], acc[s][u]);
            #pragma unroll
            for (int s = 0; s < 2; ++s)
                #pragma unroll
                for (int u = 0; u < 2; ++u)
                    acc[s][u] = MFMA(a[s], b_l[u], acc[s][u]);
        }
        __syncthreads();
    }
    #pragma unroll
    for (int s = 0; s < 2; ++s) {
        int r = row0 + wr*32 + s*16 + fg*4;
        #pragma unroll
        for (int u = 0; u < 2; ++u) {
            int c = col0 + wc*32 + u*16 + fr;
            if (c < N) {
                #pragma unroll
                for (int j = 0; j < 4; ++j) {
                    size_t o = (size_t)(r+j)*ldc + c;
                    C[o] = accum ? (C[o] + acc[s][u][j]) : acc[s][u][j];
                }
            }
        }
    }
}

// ------------- MFMA single-product GEMM, 128x64 block, wave 64x32 (proj GEMMs), T14 pipelined -------------
__global__ __launch_bounds__(256)
void mm_bt2(const ushort* __restrict__ A1, int lda1, int K1,
            const ushort* __restrict__ A2, int lda2,
            const ushort* __restrict__ Wgh,
            float* __restrict__ C, int ldc, int N, int K, int accum)
{
    __shared__ ushort As[128*32], Whs[64*32];
    int tid = threadIdx.x;
    int lane = tid & 63, wid = tid >> 6;
    int bx, by; xcd_swz(gridDim.x, gridDim.y, bx, by);
    int row0 = by*128, col0 = bx*64;
    int wr = wid >> 1, wc = wid & 1;
    int fr = lane & 15, fg = lane >> 4;
    int gsl = (fg ^ ((fr >> 1) & 3)) * 8;
    int sr = tid >> 2, sg0 = tid & 3;
    int g = sg0 ^ ((sr >> 1) & 3);
    int wrow = col0 + sr; if (wrow >= N) wrow = N - 1;

    ushort8v va[2], vh;
    auto loadk = [&](int k0) {
        const ushort* Asrc; int lda, kk;
        if (k0 < K1) { Asrc = A1; lda = lda1; kk = k0; }
        else         { Asrc = A2; lda = lda2; kk = k0 - K1; }
        #pragma unroll
        for (int i = 0; i < 2; ++i)
            va[i] = *(const ushort8v*)(Asrc + (size_t)(row0 + sr + i*64)*lda + kk + g*8);
        vh = *(const ushort8v*)(Wgh + (size_t)wrow*K + k0 + g*8);
    };

    f32x4 acc[4][2] = {};
    loadk(0);
    for (int k0 = 0; k0 < K; k0 += 32) {
        __syncthreads();
        #pragma unroll
        for (int i = 0; i < 2; ++i)
            *(ushort8v*)&As[(sr + i*64)*32 + sg0*8] = va[i];
        *(ushort8v*)&Whs[sr*32 + sg0*8] = vh;
        if (k0 + 32 < K) loadk(k0 + 32);
        __syncthreads();
        bf16x8 a[4], bh[2];
        #pragma unroll
        for (int s = 0; s < 4; ++s) {
            int r = wr*64 + s*16 + fr;
            a[s] = *(const bf16x8*)&As[r*32 + gsl];
        }
        #pragma unroll
        for (int u = 0; u < 2; ++u) {
            int r = wc*32 + u*16 + fr;
            bh[u] = *(const bf16x8*)&Whs[r*32 + gsl];
        }
        #pragma unroll
        for (int s = 0; s < 4; ++s)
            #pragma unroll
            for (int u = 0; u < 2; ++u)
                acc[s][u] = MFMA(a[s], bh[u], acc[s][u]);
    }
    #pragma unroll
    for (int s = 0; s < 4; ++s) {
        int rb = row0 + wr*64 + s*16 + fg*4;
        #pragma unroll
        for (int u = 0; u < 2; ++u) {
            int c = col0 + wc*32 + u*16 + fr;
            if (c < N) {
                #pragma unroll
                for (int j = 0; j < 4; ++j) {
                    size_t o = (size_t)(rb+j)*ldc + c;
                    C[o] = accum ? (C[o] + acc[s][u][j]) : acc[s][u][j];
                }
            }
        }
    }
}

// ------------- Fused expand GEMM, single-product: bx<nqt -> q GEMM (fp32 out), else GEGLU tile -------------
__global__ __launch_bounds__(256)
void mm_fused2(const ushort* __restrict__ Ag, int lda,
               const ushort* __restrict__ Wqh,
               int Nq, int nqt, float* __restrict__ Qout, int ldq,
               const ushort* __restrict__ W1h, const ushort* __restrict__ W2h,
               ushort* __restrict__ Oh, int ldo, int K)
{
    __shared__ ushort As[128*32];
    __shared__ ushort Xs[2][64*32];
    int tid = threadIdx.x;
    int lane = tid & 63, wid = tid >> 6;
    int bx, by; xcd_swz(gridDim.x, gridDim.y, bx, by);
    int row0 = by*128;
    int wr = wid >> 1, wc = wid & 1;
    int fr = lane & 15, fg = lane >> 4;
    int gsl = (fg ^ ((fr >> 1) & 3)) * 8;
    int sr = tid >> 2, sg0 = tid & 3;
    int g = sg0 ^ ((sr >> 1) & 3);

    if (bx < nqt) {
        int col0 = bx*64;
        int wrow = col0 + sr; if (wrow >= Nq) wrow = Nq - 1;
        ushort8v va[2], vh;
        auto loadk = [&](int k0) {
            #pragma unroll
            for (int i = 0; i < 2; ++i)
                va[i] = *(const ushort8v*)(Ag + (size_t)(row0 + sr + i*64)*lda + k0 + g*8);
            vh = *(const ushort8v*)(Wqh + (size_t)wrow*K + k0 + g*8);
        };
        f32x4 acc[4][2] = {};
        loadk(0);
        for (int k0 = 0; k0 < K; k0 += 32) {
            __syncthreads();
            #pragma unroll
            for (int i = 0; i < 2; ++i)
                *(ushort8v*)&As[(sr + i*64)*32 + sg0*8] = va[i];
            *(ushort8v*)&Xs[0][sr*32 + sg0*8] = vh;
            if (k0 + 32 < K) loadk(k0 + 32);
            __syncthreads();
            bf16x8 a[4], bh[2];
            #pragma unroll
            for (int s = 0; s < 4; ++s) {
                int r = wr*64 + s*16 + fr;
                a[s] = *(const bf16x8*)&As[r*32 + gsl];
            }
            #pragma unroll
            for (int u = 0; u < 2; ++u) {
                int r = wc*32 + u*16 + fr;
                bh[u] = *(const bf16x8*)&Xs[0][r*32 + gsl];
            }
            #pragma unroll
            for (int s = 0; s < 4; ++s)
                #pragma unroll
                for (int u = 0; u < 2; ++u)
                    acc[s][u] = MFMA(a[s], bh[u], acc[s][u]);
        }
        #pragma unroll
        for (int s = 0; s < 4; ++s) {
            int rb = row0 + wr*64 + s*16 + fg*4;
            #pragma unroll
            for (int u = 0; u < 2; ++u) {
                int c = col0 + wc*32 + u*16 + fr;
                if (c < Nq) {
                    #pragma unroll
                    for (int j = 0; j < 4; ++j)
                        Qout[(size_t)(rb+j)*ldq + c] = acc[s][u][j];
                }
            }
        }
    } else {
        int col0 = (bx - nqt)*64;
        ushort8v va[2], vw0, vw2;
        auto loadk = [&](int k0) {
            #pragma unroll
            for (int i = 0; i < 2; ++i)
                va[i] = *(const ushort8v*)(Ag + (size_t)(row0 + sr + i*64)*lda + k0 + g*8);
            size_t wro = (size_t)(col0 + sr)*K + k0 + g*8;
            vw0 = *(const ushort8v*)(W1h + wro);
            vw2 = *(const ushort8v*)(W2h + wro);
        };
        f32x4 acc1[4][2] = {}, acc2[4][2] = {};
        loadk(0);
        for (int k0 = 0; k0 < K; k0 += 32) {
            __syncthreads();
            #pragma unroll
            for (int i = 0; i < 2; ++i)
                *(ushort8v*)&As[(sr + i*64)*32 + sg0*8] = va[i];
            {
                int o = sr*32 + sg0*8;
                *(ushort8v*)&Xs[0][o] = vw0;
                *(ushort8v*)&Xs[1][o] = vw2;
            }
            if (k0 + 32 < K) loadk(k0 + 32);
            __syncthreads();
            bf16x8 a[4], b1[2], b2[2];
            #pragma unroll
            for (int s = 0; s < 4; ++s) {
                int r = wr*64 + s*16 + fr;
                a[s] = *(const bf16x8*)&As[r*32 + gsl];
            }
            #pragma unroll
            for (int u = 0; u < 2; ++u) {
                int r = wc*32 + u*16 + fr;
                b1[u] = *(const bf16x8*)&Xs[0][r*32 + gsl];
                b2[u] = *(const bf16x8*)&Xs[1][r*32 + gsl];
            }
            #pragma unroll
            for (int s = 0; s < 4; ++s)
                #pragma unroll
                for (int u = 0; u < 2; ++u) {
                    acc1[s][u] = MFMA(a[s], b1[u], acc1[s][u]);
                    acc2[s][u] = MFMA(a[s], b2[u], acc2[s][u]);
                }
        }
        #pragma unroll
        for (int s = 0; s < 4; ++s) {
            int rb = row0 + wr*64 + s*16 + fg*4;
            #pragma unroll
            for (int u = 0; u < 2; ++u) {
                int c = col0 + wc*32 + u*16 + fr;
                #pragma unroll
                for (int j = 0; j < 4; ++j) {
                    float gg = acc1[s][u][j] * gelu_f(acc2[s][u][j]);
                    Oh[(size_t)(rb+j)*ldo + c] = f2b(gg);
                }
            }
        }
    }
}

// ------------- batched pk GEMM (2-product, precomputed once): P12[z] = ptp @ Wkv[z]^T -------------
__global__ __launch_bounds__(256)
void pk_mm(const ushort* __restrict__ A,
           const ushort* __restrict__ Wh_, const ushort* __restrict__ Wl_,
           float* __restrict__ P12)
{
    __shared__ ushort Ah[64][72], Wh[64][72], Wl[64][72];
    int tid = threadIdx.x;
    int z = blockIdx.z, blk = z >> 1, half = z & 1;
    int row0 = blockIdx.y*64, col0 = blockIdx.x*64;
    int srow = tid >> 3, sseg = (tid & 7) * 8;
    int wid = tid >> 6, lane = tid & 63;
    int wr = wid >> 1, wc = wid & 1;
    int fr = lane & 15, fg = lane >> 4;
    const ushort* Wbh = Wh_ + (size_t)blk*816*384 + half*192;
    const ushort* Wbl = Wl_ + (size_t)blk*816*384 + half*192;
    float* C = P12 + (size_t)z*128*816;
    f32x4 acc[2][2] = {};
    for (int k0 = 0; k0 < 192; k0 += 64) {
        ushort8v va[2], vc[2], vd[2];
        #pragma unroll
        for (int p = 0; p < 2; ++p) {
            int r = p*32 + srow;
            int wrow = col0 + r; if (wrow >= 816) wrow = 815;
            int gk = k0 + sseg;
            va[p] = *(const ushort8v*)(A + (size_t)(row0 + r)*192 + gk);
            vc[p] = *(const ushort8v*)(Wbh + (size_t)wrow*384 + gk);
            vd[p] = *(const ushort8v*)(Wbl + (size_t)wrow*384 + gk);
        }
        __syncthreads();
        #pragma unroll
        for (int p = 0; p < 2; ++p) {
            int r = p*32 + srow;
            *(ushort8v*)&Ah[r][sseg] = va[p];
            *(ushort8v*)&Wh[r][sseg] = vc[p];
            *(ushort8v*)&Wl[r][sseg] = vd[p];
        }
        __syncthreads();
        #pragma unroll
        for (int kk = 0; kk < 64; kk += 32) {
            bf16x8 a[2], b_h[2], b_l[2];
            #pragma unroll
            for (int s = 0; s < 2; ++s) {
                a[s]   = *(const bf16x8*)&Ah[wr*32 + s*16 + fr][kk + fg*8];
                b_h[s] = *(const bf16x8*)&Wh[wc*32 + s*16 + fr][kk + fg*8];
                b_l[s] = *(const bf16x8*)&Wl[wc*32 + s*16 + fr][kk + fg*8];
            }
            #pragma unroll
            for (int s = 0; s < 2; ++s)
                #pragma unroll
                for (int u = 0; u < 2; ++u)
                    acc[s][u] = MFMA(a[s], b_h[u], acc[s][u]);
            #pragma unroll
            for (int s = 0; s < 2; ++s)
                #pragma unroll
                for (int u = 0; u < 2; ++u)
                    acc[s][u] = MFMA(a[s], b_l[u], acc[s][u]);
        }
        __syncthreads();
    }
    #pragma unroll
    for (int s = 0; s < 2; ++s) {
        int r = row0 + wr*32 + s*16 + fg*4;
        #pragma unroll
        for (int u = 0; u < 2; ++u) {
            int c = col0 + wc*32 + u*16 + fr;
            if (c < 816) {
                #pragma unroll
                for (int j = 0; j < 4; ++j)
                    C[(size_t)(r+j)*816 + c] = acc[s][u][j];
            }
        }
    }
}

// ------------- MFMA batched PV v2: 64x128 block, wave 64x32, T14 pipelined -------------
// XCD swizzle: all blocks of one batch (same z) share V/P panels -> same XCD.
__global__ __launch_bounds__(256)
void pv2(const ushort* __restrict__ P, int ldp, long sP,
         const ushort* __restrict__ V, int ldv, long sV,
         ushort* __restrict__ Oh, int ldo, long sO,
         int Mrows, int K, int Kv)
{
    __shared__ ushort Ps[64][40];
    __shared__ ushort Vs[128*32];
    int L = blockIdx.x + gridDim.x*(blockIdx.y + gridDim.y*blockIdx.z);
    int gz = gridDim.z;
    int zz = L % gz;                    // gz=128 (multiple of 8) -> same zz => same XCD
    int rest = L / gz;
    int bx = rest % gridDim.x;
    int byy = rest / gridDim.x;
    const ushort* Pb = P + (size_t)zz * sP;
    const ushort* Vb = V + (size_t)zz * sV;
    ushort* Ohb = Oh + (size_t)zz * sO;
    int tid = threadIdx.x;
    int row0 = byy*64, col0 = bx*128;
    int wid = tid >> 6, lane = tid & 63;
    int fr = lane & 15, fg = lane >> 4;
    int prow = tid >> 2, pseg = (tid & 3) * 8;
    int vk = tid & 31, vcb = (tid >> 5) * 8;

    ushort8v pv_, vv[2];
    auto loadk = [&](int k0) {
        pv_ = (ushort8v){0,0,0,0,0,0,0,0};
        int grow = row0 + prow;
        if (grow < Mrows)
            pv_ = *(const ushort8v*)(Pb + (size_t)grow*ldp + k0 + pseg);
        vv[0] = (ushort8v){0,0,0,0,0,0,0,0};
        vv[1] = (ushort8v){0,0,0,0,0,0,0,0};
        int gk = k0 + vk;
        if (gk < Kv) {
            #pragma unroll
            for (int i = 0; i < 2; ++i)
                vv[i] = *(const ushort8v*)(Vb + (size_t)gk*ldv + col0 + vcb + i*64);
        }
    };

    f32x4 acc[4][2] = {};
    loadk(0);
    for (int k0 = 0; k0 < K; k0 += 32) {
        __syncthreads();
        *(ushort8v*)&Ps[prow][pseg] = pv_;
        #pragma unroll
        for (int i = 0; i < 2; ++i) {
            #pragma unroll
            for (int e = 0; e < 8; ++e) {
                int c = vcb + i*64 + e;
                Vs[c*32 + (vk & 7) + 8*((vk >> 3) ^ ((c >> 3) & 3))] = vv[i][e];
            }
        }
        if (k0 + 32 < K) loadk(k0 + 32);
        __syncthreads();
        bf16x8 a[4], b[2];
        #pragma unroll
        for (int s = 0; s < 4; ++s)
            a[s] = *(const bf16x8*)&Ps[s*16 + fr][fg*8];
        #pragma unroll
        for (int u = 0; u < 2; ++u) {
            int c = wid*32 + u*16 + fr;
            b[u] = *(const bf16x8*)&Vs[c*32 + 8*(fg ^ ((c >> 3) & 3))];
        }
        #pragma unroll
        for (int s = 0; s < 4; ++s)
            #pragma unroll
            for (int u = 0; u < 2; ++u)
                acc[s][u] = MFMA(a[s], b[u], acc[s][u]);
    }
    #pragma unroll
    for (int s = 0; s < 4; ++s) {
        int rbase = row0 + s*16 + fg*4;
        #pragma unroll
        for (int u = 0; u < 2; ++u) {
            int c = col0 + wid*32 + u*16 + fr;
            #pragma unroll
            for (int j = 0; j < 4; ++j) {
                int r = rbase + j;
                if (r < Mrows)
                    Ohb[(size_t)r*ldo + c] = f2b(acc[s][u][j]);
            }
        }
    }
}

// ------------- MFMA attention scores + softmax -> normalized P (bf16) -------------
// grid (2, B_): row slab (64 rows), batch. Score/softmax logic identical to the
// round-21 verified fused kernel; standalone (no col-tile redundancy).
template<int NK, int CAUSAL>
__global__ __launch_bounds__(256)
void attn_score_mfma(const float* __restrict__ Q, int ldq, long sQ,
                     const float* __restrict__ Kf, int ldk, int koff, long sK,
                     ushort* __restrict__ P,
                     const float* __restrict__ bm, int blk, int Kv)
{
    constexpr int NKF = NK / 16;
    __shared__ ushort Qs[64*72];
    __shared__ ushort Ks[NK*72];
    int slab = blockIdx.x;
    int zz = blockIdx.y;
    int row0 = slab*64;
    int tid = threadIdx.x;
    int wv = tid >> 6, lane = tid & 63;
    int fr = lane & 15, fg = lane >> 4;

    const float scale = 0.14433756729740643f;
    float sp = 0.f;
    if (CAUSAL) { float bmv = bm[blk]; sp = (bmv > 20.f) ? bmv : log1pf(expf(bmv)); }

    const float* Qb = Q + (size_t)zz * sQ;
    for (int idx = tid; idx < 64*64; idx += 256) {
        int r = idx >> 6, c = idx & 63;
        int grow = row0 + r; if (grow >= S_) grow = S_ - 1;
        ushort v = 0;
        if (c < 48) v = f2b(Qb[(size_t)grow*ldq + c]);
        Qs[r*72 + c] = v;
    }
    const float* Kb = Kf + (size_t)zz*sK + koff;
    for (int idx = tid; idx < NK*64; idx += 256) {
        int j = idx >> 6, c = idx & 63;
        ushort v = 0;
        if (c < 48 && j < Kv) v = f2b(Kb[(size_t)j*ldk + c]);
        Ks[j*72 + c] = v;
    }
    __syncthreads();

    f32x4 sacc[NKF];
    #pragma unroll
    for (int kf = 0; kf < NKF; ++kf) sacc[kf] = (f32x4){0.f,0.f,0.f,0.f};
    bf16x8 aq0 = *(const bf16x8*)&Qs[(wv*16 + fr)*72 +  0 + fg*8];
    bf16x8 aq1 = *(const bf16x8*)&Qs[(wv*16 + fr)*72 + 32 + fg*8];
    #pragma unroll
    for (int kf = 0; kf < NKF; ++kf) {
        bf16x8 bk0 = *(const bf16x8*)&Ks[(kf*16 + fr)*72 +  0 + fg*8];
        bf16x8 bk1 = *(const bf16x8*)&Ks[(kf*16 + fr)*72 + 32 + fg*8];
        sacc[kf] = MFMA(aq0, bk0, sacc[kf]);
        sacc[kf] = MFMA(aq1, bk1, sacc[kf]);
    }
    #pragma unroll
    for (int j = 0; j < 4; ++j) {
        int i = row0 + wv*16 + fg*4 + j;
        float m = -1e30f;
        #pragma unroll
        for (int kf = 0; kf < NKF; ++kf) {
            int key = kf*16 + fr;
            float s = sacc[kf][j] * scale;
            if (CAUSAL) s = (key <= i) ? (s + sp*(float)(key - i)) : -1e30f;
            sacc[kf][j] = s;
            m = fmaxf(m, s);
        }
        #pragma unroll
        for (int off = 1; off < 16; off <<= 1) m = fmaxf(m, __shfl_xor(m, off));
        float sum = 0.f;
        #pragma unroll
        for (int kf = 0; kf < NKF; ++kf) {
            float p = __expf(sacc[kf][j] - m);
            sacc[kf][j] = p;
            sum += p;
        }
        #pragma unroll
        for (int off = 1; off < 16; off <<= 1) sum += __shfl_xor(sum, off);
        float inv = 1.f / sum;
        if (i < S_) {
            ushort* prow = P + ((size_t)(zz*S_) + i)*NK;
            #pragma unroll
            for (int kf = 0; kf < NKF; ++kf)
                prow[kf*16 + fr] = f2b(sacc[kf][j] * inv);
        }
    }
}

// ------------- gather pk rows -> k2 (fp32), geglu'd values gv (bf16) -------------
__global__ __launch_bounds__(256)
void pk_gather(const int* __restrict__ pts, const float* __restrict__ P12, int blk,
               float* __restrict__ k2, ushort* __restrict__ gv)
{
    int pair = blockIdx.x*4 + (threadIdx.x >> 6);
    int lane = threadIdx.x & 63;
    const float* P1 = P12 + (size_t)(blk*2 + 0)*128*816;
    const float* P2 = P12 + (size_t)(blk*2 + 1)*128*816;
    int t0 = pts[2*pair], t1 = pts[2*pair+1];
    const float* a = P1 + (size_t)t0*816;
    const float* c = P2 + (size_t)t1*816;
    if (lane < QK_) k2[(size_t)pair*QK_ + lane] = a[lane] + c[lane];
    #pragma unroll
    for (int t = 0; t < 6; ++t) {
        int i = lane + 64*t;
        float lin = a[48 + i] + c[48 + i];
        float pre = a[432 + i] + c[432 + i];
        gv[(size_t)pair*D_ + i] = f2b(lin * gelu_f(pre));
    }
}

// all layers at once: blockIdx.y = layer
__global__ __launch_bounds__(256)
void pk_gather_all(const int* __restrict__ pts, const float* __restrict__ P12,
                   float* __restrict__ k2, ushort* __restrict__ gv)
{
    int pair = blockIdx.x*4 + (threadIdx.x >> 6);
    int lane = threadIdx.x & 63;
    int blk = blockIdx.y;
    const float* P1 = P12 + (size_t)(blk*2 + 0)*128*816;
    const float* P2 = P12 + (size_t)(blk*2 + 1)*128*816;
    float* k2b = k2 + (size_t)blk*B_*NPTS_*QK_;
    ushort* gvb = gv + (size_t)blk*B_*NPTS_*D_;
    int t0 = pts[2*pair], t1 = pts[2*pair+1];
    const float* a = P1 + (size_t)t0*816;
    const float* c = P2 + (size_t)t1*816;
    if (lane < QK_) k2b[(size_t)pair*QK_ + lane] = a[lane] + c[lane];
    #pragma unroll
    for (int t = 0; t < 6; ++t) {
        int i = lane + 64*t;
        float lin = a[48 + i] + c[48 + i];
        float pre = a[432 + i] + c[432 + i];
        gvb[(size_t)pair*D_ + i] = f2b(lin * gelu_f(pre));
    }
}

extern "C" void kernel_launch(void* const* d_in, const int* in_sizes, int n_in,
                              void* d_out, int out_size, void* d_ws, size_t ws_size,
                              hipStream_t stream)
{
    const int*   qtok  = (const int*)d_in[0];
    const int*   pts   = (const int*)d_in[1];
    const float* emb   = (const float*)d_in[2];
    const float* ptemb = (const float*)d_in[3];
    const float* normw = (const float*)d_in[4];
    const float* outw  = (const float*)d_in[5];
    const float* ln1   = (const float*)d_in[6];
    const float* expand= (const float*)d_in[7];
    const float* proj1 = (const float*)d_in[8];
    const float* bm    = (const float*)d_in[9];
    const float* ln2   = (const float*)d_in[10];
    const float* Wq    = (const float*)d_in[11];
    const float* Wkv   = (const float*)d_in[12];
    const float* proj2 = (const float*)d_in[13];
    float* out = (float*)d_out;

    char* base = (char*)d_ws;
    size_t off = 0;
    auto alloc = [&](size_t bytes){ void* p = base + off; off += (bytes + 255) & ~(size_t)255; return p; };
    float*  h     = (float*) alloc((size_t)M_*D_*4);
    ushort* nh    = (ushort*)alloc((size_t)M_*D_*2);
    float*  qk1   = (float*) alloc((size_t)M_*96*4);     // qr2 aliases
    ushort* gegl  = (ushort*)alloc((size_t)M_*E_*2);     // gloc aliases
    ushort* atb   = (ushort*)alloc((size_t)M_*D_*2);
    ushort* Pbuf  = (ushort*)alloc((size_t)M_*256*2);
    float*  P12   = (float*) alloc((size_t)16*128*816*4);
    ushort* wkvh  = (ushort*)alloc((size_t)NB_*816*384*2);
    ushort* wkvl  = (ushort*)alloc((size_t)NB_*816*384*2);
    ushort* ptp   = (ushort*)alloc((size_t)128*192*2);
    ushort* obh   = (ushort*)alloc((size_t)NTOK_*D_*2);
    ushort* obl   = (ushort*)alloc((size_t)NTOK_*D_*2);

    // weight buffer (hi only): all 8 layers if workspace allows, else single-layer
    size_t rem = (ws_size > off) ? (ws_size - off) : 0;
    bool fits8 = rem >= ((size_t)NB_ * WTOT * 2
                         + (size_t)B_*NPTS_*D_*2 + (size_t)B_*NPTS_*QK_*4 + 4096);
    int nlay = fits8 ? NB_ : 1;
    ushort* wbh = (ushort*)alloc((size_t)nlay*WTOT*2);
    size_t wstride = fits8 ? (size_t)WTOT : 0;

    // pk-gather buffers: all 8 layers if workspace allows (hoist), else per-layer
    size_t gv_l = (size_t)B_*NPTS_*D_;   // elements (ushort)
    size_t k2_l = (size_t)B_*NPTS_*QK_;  // elements (float)
    size_t rem2 = (ws_size > off) ? (ws_size - off) : 0;
    bool fitsPK = rem2 >= ((size_t)NB_*gv_l*2 + (size_t)NB_*k2_l*4 + 4096);
    int play = fitsPK ? NB_ : 1;
    ushort* gvB = (ushort*)alloc((size_t)play*gv_l*2);
    float*  k2B = (float*) alloc((size_t)play*k2_l*4);
    size_t gvs = fitsPK ? gv_l : 0;
    size_t k2s = fitsPK ? k2_l : 0;

    float*  qr2   = qk1;
    ushort* gloc  = gegl;

    const size_t oWE = 0;
    const size_t oP1 = WE_SZ;
    const size_t oWQ = WE_SZ + P1_SZ;
    const size_t oP2 = WE_SZ + P1_SZ + WQ_SZ;

    x_init<<<M_/4, 256, 0, stream>>>(qtok, emb, normw, h, M_);
    pconv<<<(128*192 + 255)/256, 256, 0, stream>>>(ptemb, ptp);
    wconv1<<<(NB_*816*384 + 255)/256, 256, 0, stream>>>(Wkv, NB_*816*384, wkvh, wkvl);
    pk_mm<<<dim3(13, 2, 16), 256, 0, stream>>>(ptp, wkvh, wkvl, P12);
    if (fits8)
        wconv_all_hi<<<dim3((WTOT+255)/256, NB_), 256, 0, stream>>>(
            expand, proj1, Wq, proj2, wbh);
    if (fitsPK)
        pk_gather_all<<<dim3(B_*NPTS_/4, NB_), 256, 0, stream>>>(pts, P12, k2B, gvB);

    for (int blk = 0; blk < NB_; ++blk) {
        if (!fits8)
            wconv_hi<<<(WTOT+255)/256, 256, 0, stream>>>(
                expand + (size_t)blk*WE_SZ, proj1 + (size_t)blk*P1_SZ,
                Wq + (size_t)blk*WQ_SZ, proj2 + (size_t)blk*P2_SZ, wbh);
        const ushort* Lh = wbh + wstride*blk;
        ushort* gv = gvB + gvs*blk;
        float*  k2 = k2B + k2s*blk;

        ln_rows<<<M_/4, 256, 0, stream>>>(h, ln1 + blk*D_, nh, M_);
        // fused: qk (N=96 -> 2 tiles) + geglu768 (12 tiles)
        mm_fused2<<<dim3(14, M_/128), 256, 0, stream>>>(nh, D_,
            Lh + oWE, 96, 2, qk1, 96,
            Lh + oWE + (size_t)96*D_, Lh + oWE + (size_t)864*D_,
            gegl, E_, D_);
        // MFMA scores + softmax (causal + linear bias), keys padded 100->128
        attn_score_mfma<128,1><<<dim3(2, B_), 256, 0, stream>>>(
            qk1, 96, (long)S_*96,
            qk1, 96, 48, (long)S_*96,
            Pbuf, bm, blk, S_);
        pv2<<<dim3(3,2,B_), 256, 0, stream>>>(Pbuf, 128, (long)S_*128,
            gegl + LOCAL_, E_, (long)S_*E_,
            atb, D_, (long)S_*D_, S_, 128, S_);
        // h += [geglu_local | attn] @ W_p1^T
        mm_bt2<<<dim3(6, M_/128), 256, 0, stream>>>(gegl, E_, D_, atb, D_,
            Lh + oP1, h, D_, D_, E_, 1);

        ln_rows<<<M_/4, 256, 0, stream>>>(h, ln2 + blk*D_, nh, M_);
        // fused: qr2 (N=48 -> 1 tile) + geglu384 (6 tiles)
        mm_fused2<<<dim3(7, M_/128), 256, 0, stream>>>(nh, D_,
            Lh + oWQ, 48, 1, qr2, 48,
            Lh + oWQ + (size_t)48*D_, Lh + oWQ + (size_t)432*D_,
            gloc, D_, D_);
        // pk path (P12 precomputed; gather hoisted if it fits)
        if (!fitsPK)
            pk_gather<<<B_*NPTS_/4, 256, 0, stream>>>(pts, P12, blk, k2, gv);
        // MFMA scores + softmax (no mask), 256 keys
        attn_score_mfma<256,0><<<dim3(2, B_), 256, 0, stream>>>(
            qr2, 48, (long)S_*48,
            k2, 48, 0, (long)NPTS_*48,
            Pbuf, bm, blk, NPTS_);
        pv2<<<dim3(3,2,B_), 256, 0, stream>>>(Pbuf, 256, (long)S_*256,
            gv, D_, (long)NPTS_*D_,
            atb, D_, (long)S_*D_, S_, 256, 256);
        // h += [g_local | attn2] @ W_p2^T
        mm_bt2<<<dim3(6, M_/128), 256, 0, stream>>>(gloc, D_, D_, atb, D_,
            Lh + oP2, h, D_, D_, E_, 1);
    }

    ln_rows<<<M_/4, 256, 0, stream>>>(h, normw, nh, M_);
    wconv1<<<(NTOK_*D_ + 255)/256, 256, 0, stream>>>(outw, NTOK_*D_, obh, obl);
    mm_bt64<<<dim3(2, M_/64), 256, 0, stream>>>(nh, D_, D_, nh, D_,
        obh, obl, out, NTOK_, NTOK_, D_, 0);
}

// Round 25
// 1645.722 us; speedup vs baseline: 1.0073x; 1.0025x over previous
//
#include <hip/hip_runtime.h>
#include <hip/hip_bf16.h>
#include <math.h>

#define B_    128
#define S_    100
#define D_    384
#define QK_   48
#define E_    768
#define LOCAL_ 384
#define NB_   8
#define NTOK_ 100
#define NPTS_ 256
#define M_    (B_*S_)   // 12800

typedef unsigned short ushort;
typedef __attribute__((ext_vector_type(8))) short  bf16x8;
typedef __attribute__((ext_vector_type(8))) unsigned short ushort8v;
typedef __attribute__((ext_vector_type(4))) float  f32x4;

#define MFMA(a,b,c) __builtin_amdgcn_mfma_f32_16x16x32_bf16(a,b,c,0,0,0)

// fast GELU (tanh form): max |diff vs exact erf-GELU| ~3e-4, well under tolerance
static __device__ __forceinline__ float gelu_f(float x) {
    float y = 1.5957691216057308f * (x + 0.044715f * x * x * x);
    float e = __expf(y);
    float t = 1.0f - 2.0f / (e + 1.0f);
    return 0.5f * x * (1.0f + t);
}
static __device__ __forceinline__ ushort f2b(float f) {
    union { float f; unsigned u; } x; x.f = f;
    unsigned r = x.u + 0x7FFFu + ((x.u >> 16) & 1u);
    return (ushort)(r >> 16);
}
static __device__ __forceinline__ float b2f(ushort u) {
    union { unsigned u; float f; } x; x.u = ((unsigned)u) << 16;
    return x.f;
}

// XCD-locality swizzle: group row-panels (by) in chunks of 8 so all col-tiles (bx)
// of one panel land on the same XCD.
static __device__ __forceinline__ void xcd_swz(int xn, int gy, int& bx, int& by) {
    int L = blockIdx.x + xn * blockIdx.y;
    int gmain = (gy & ~7) * xn;
    if (L < gmain) {
        int grp = L / (8 * xn);
        int r = L % (8 * xn);
        bx = r >> 3;
        by = grp * 8 + (r & 7);
    } else {
        int Lp = L - gmain;
        int tail = gy & 7;
        by = (gy & ~7) + (Lp % tail);
        bx = Lp / tail;
    }
}

// ---------------- LayerNorm: fp32 in -> bf16 out ----------------
__global__ __launch_bounds__(256)
void ln_rows(const float* __restrict__ X, const float* __restrict__ w,
             ushort* __restrict__ Y, int nrows)
{
    int row = blockIdx.x * 4 + (threadIdx.x >> 6);
    if (row >= nrows) return;
    int lane = threadIdx.x & 63;
    const float* x = X + (size_t)row * D_;
    float v[6]; float s = 0.f;
    #pragma unroll
    for (int t = 0; t < 6; ++t) { v[t] = x[lane + 64*t]; s += v[t]; }
    #pragma unroll
    for (int off = 32; off; off >>= 1) s += __shfl_xor(s, off);
    float mu = s * (1.f/(float)D_);
    float q = 0.f;
    #pragma unroll
    for (int t = 0; t < 6; ++t) { float d = v[t]-mu; q += d*d; }
    #pragma unroll
    for (int off = 32; off; off >>= 1) q += __shfl_xor(q, off);
    float rs = rsqrtf(q * (1.f/(float)D_) + 1e-5f);
    #pragma unroll
    for (int t = 0; t < 6; ++t)
        Y[(size_t)row*D_ + lane + 64*t] = f2b((v[t]-mu)*rs*w[lane + 64*t]);
}

// ------------- gather emb[q] + LayerNorm -> fp32 h -------------
__global__ __launch_bounds__(256)
void x_init(const int* __restrict__ qtok, const float* __restrict__ emb,
            const float* __restrict__ w, float* __restrict__ Y, int nrows)
{
    int row = blockIdx.x * 4 + (threadIdx.x >> 6);
    if (row >= nrows) return;
    int lane = threadIdx.x & 63;
    const float* x = emb + (size_t)qtok[row] * D_;
    float v[6]; float s = 0.f;
    #pragma unroll
    for (int t = 0; t < 6; ++t) { v[t] = x[lane + 64*t]; s += v[t]; }
    #pragma unroll
    for (int off = 32; off; off >>= 1) s += __shfl_xor(s, off);
    float mu = s * (1.f/(float)D_);
    float q = 0.f;
    #pragma unroll
    for (int t = 0; t < 6; ++t) { float d = v[t]-mu; q += d*d; }
    #pragma unroll
    for (int off = 32; off; off >>= 1) q += __shfl_xor(q, off);
    float rs = rsqrtf(q * (1.f/(float)D_) + 1e-5f);
    float* y = Y + (size_t)row * D_;
    #pragma unroll
    for (int t = 0; t < 6; ++t) y[lane + 64*t] = (v[t]-mu)*rs*w[lane + 64*t];
}

// ------------- weight conversion -------------
#define WE_SZ  (1632*384)
#define P1_SZ  (384*768)
#define WQ_SZ  (816*384)
#define P2_SZ  (384*768)
#define WTOT   (WE_SZ + P1_SZ + WQ_SZ + P2_SZ)

static __device__ __forceinline__ void wsplit(float v, ushort* wh, ushort* wl, size_t o) {
    ushort h = f2b(v);
    wh[o] = h; wl[o] = f2b(v - b2f(h));
}

// all layers at once, hi only (plain bf16 weights): blockIdx.y = layer
__global__ __launch_bounds__(256)
void wconv_all_hi(const float* __restrict__ expand, const float* __restrict__ proj1,
                  const float* __restrict__ wq, const float* __restrict__ proj2,
                  ushort* __restrict__ wh)
{
    int i = blockIdx.x*256 + threadIdx.x;
    if (i >= WTOT) return;
    int blk = blockIdx.y;
    float v;
    if (i < WE_SZ) v = expand[(size_t)blk*WE_SZ + i];
    else if (i < WE_SZ+P1_SZ) v = proj1[(size_t)blk*P1_SZ + (i - WE_SZ)];
    else if (i < WE_SZ+P1_SZ+WQ_SZ) v = wq[(size_t)blk*WQ_SZ + (i - WE_SZ - P1_SZ)];
    else v = proj2[(size_t)blk*P2_SZ + (i - WE_SZ - P1_SZ - WQ_SZ)];
    wh[(size_t)blk*WTOT + i] = f2b(v);
}

__global__ __launch_bounds__(256)
void wconv_hi(const float* __restrict__ we, const float* __restrict__ p1,
              const float* __restrict__ wq, const float* __restrict__ p2,
              ushort* __restrict__ wh)
{
    int i = blockIdx.x*256 + threadIdx.x;
    if (i >= WTOT) return;
    float v;
    if (i < WE_SZ) v = we[i];
    else if (i < WE_SZ+P1_SZ) v = p1[i - WE_SZ];
    else if (i < WE_SZ+P1_SZ+WQ_SZ) v = wq[i - WE_SZ - P1_SZ];
    else v = p2[i - WE_SZ - P1_SZ - WQ_SZ];
    wh[i] = f2b(v);
}

__global__ __launch_bounds__(256)
void wconv1(const float* __restrict__ src, int n,
            ushort* __restrict__ wh, ushort* __restrict__ wl)
{
    int i = blockIdx.x*256 + threadIdx.x;
    if (i >= n) return;
    wsplit(src[i], wh, wl, i);
}

// ------------- pt_emb -> bf16, padded to 128 rows -------------
__global__ __launch_bounds__(256)
void pconv(const float* __restrict__ src, ushort* __restrict__ dst)
{
    int i = blockIdx.x*256 + threadIdx.x;
    if (i >= 128*192) return;
    int r = i / 192;
    dst[i] = (r < NTOK_) ? f2b(src[i]) : 0;
}

// ------------- MFMA 2-product GEMM, 64x64 block (final out GEMM, accuracy-critical) -------------
__global__ __launch_bounds__(256)
void mm_bt64(const ushort* __restrict__ A1, int lda1, int K1,
             const ushort* __restrict__ A2, int lda2,
             const ushort* __restrict__ Wgh, const ushort* __restrict__ Wgl,
             float* __restrict__ C, int ldc, int N, int K, int accum)
{
    __shared__ ushort Ah[64][72], Wh[64][72], Wl[64][72];
    int tid = threadIdx.x;
    int row0 = blockIdx.y*64, col0 = blockIdx.x*64;
    int srow = tid >> 3;
    int sseg = (tid & 7) * 8;
    int wid = tid >> 6, lane = tid & 63;
    int wr = wid >> 1, wc = wid & 1;
    int fr = lane & 15, fg = lane >> 4;
    f32x4 acc[2][2] = {};
    for (int k0 = 0; k0 < K; k0 += 64) {
        ushort8v va[2], vc[2], vd[2];
        #pragma unroll
        for (int p = 0; p < 2; ++p) {
            int r = p*32 + srow;
            int arow = row0 + r;
            int wrow = col0 + r;
            int gk = k0 + sseg;
            if (gk < K1) va[p] = *(const ushort8v*)(A1 + (size_t)arow*lda1 + gk);
            else         va[p] = *(const ushort8v*)(A2 + (size_t)arow*lda2 + (gk-K1));
            if (wrow >= N) wrow = N - 1;
            vc[p] = *(const ushort8v*)(Wgh + (size_t)wrow*K + gk);
            vd[p] = *(const ushort8v*)(Wgl + (size_t)wrow*K + gk);
        }
        __syncthreads();
        #pragma unroll
        for (int p = 0; p < 2; ++p) {
            int r = p*32 + srow;
            *(ushort8v*)&Ah[r][sseg] = va[p];
            *(ushort8v*)&Wh[r][sseg] = vc[p];
            *(ushort8v*)&Wl[r][sseg] = vd[p];
        }
        __syncthreads();
        #pragma unroll
        for (int kk = 0; kk < 64; kk += 32) {
            bf16x8 a[2], b_h[2], b_l[2];
            #pragma unroll
            for (int s = 0; s < 2; ++s) {
                a[s]   = *(const bf16x8*)&Ah[wr*32 + s*16 + fr][kk + fg*8];
                b_h[s] = *(const bf16x8*)&Wh[wc*32 + s*16 + fr][kk + fg*8];
                b_l[s] = *(const bf16x8*)&Wl[wc*32 + s*16 + fr][kk + fg*8];
            }
            #pragma unroll
            for (int s = 0; s < 2; ++s)
                #pragma unroll
                for (int u = 0; u < 2; ++u)
                    acc[s][u] = MFMA(a[s], b_h[u], acc[s][u]);
            #pragma unroll
            for (int s = 0; s < 2; ++s)
                #pragma unroll
                for (int u = 0; u < 2; ++u)
                    acc[s][u] = MFMA(a[s], b_l[u], acc[s][u]);
        }
        __syncthreads();
    }
    #pragma unroll
    for (int s = 0; s < 2; ++s) {
        int r = row0 + wr*32 + s*16 + fg*4;
        #pragma unroll
        for (int u = 0; u < 2; ++u) {
            int c = col0 + wc*32 + u*16 + fr;
            if (c < N) {
                #pragma unroll
                for (int j = 0; j < 4; ++j) {
                    size_t o = (size_t)(r+j)*ldc + c;
                    C[o] = accum ? (C[o] + acc[s][u][j]) : acc[s][u][j];
                }
            }
        }
    }
}

// ------------- MFMA single-product GEMM, 128x64 block, wave 64x32 (proj GEMMs), T14 pipelined -------------
__global__ __launch_bounds__(256)
void mm_bt2(const ushort* __restrict__ A1, int lda1, int K1,
            const ushort* __restrict__ A2, int lda2,
            const ushort* __restrict__ Wgh,
            float* __restrict__ C, int ldc, int N, int K, int accum)
{
    __shared__ ushort As[128*32], Whs[64*32];
    int tid = threadIdx.x;
    int lane = tid & 63, wid = tid >> 6;
    int bx, by; xcd_swz(gridDim.x, gridDim.y, bx, by);
    int row0 = by*128, col0 = bx*64;
    int wr = wid >> 1, wc = wid & 1;
    int fr = lane & 15, fg = lane >> 4;
    int gsl = (fg ^ ((fr >> 1) & 3)) * 8;
    int sr = tid >> 2, sg0 = tid & 3;
    int g = sg0 ^ ((sr >> 1) & 3);
    int wrow = col0 + sr; if (wrow >= N) wrow = N - 1;

    ushort8v va[2], vh;
    auto loadk = [&](int k0) {
        const ushort* Asrc; int lda, kk;
        if (k0 < K1) { Asrc = A1; lda = lda1; kk = k0; }
        else         { Asrc = A2; lda = lda2; kk = k0 - K1; }
        #pragma unroll
        for (int i = 0; i < 2; ++i)
            va[i] = *(const ushort8v*)(Asrc + (size_t)(row0 + sr + i*64)*lda + kk + g*8);
        vh = *(const ushort8v*)(Wgh + (size_t)wrow*K + k0 + g*8);
    };

    f32x4 acc[4][2] = {};
    loadk(0);
    for (int k0 = 0; k0 < K; k0 += 32) {
        __syncthreads();
        #pragma unroll
        for (int i = 0; i < 2; ++i)
            *(ushort8v*)&As[(sr + i*64)*32 + sg0*8] = va[i];
        *(ushort8v*)&Whs[sr*32 + sg0*8] = vh;
        if (k0 + 32 < K) loadk(k0 + 32);
        __syncthreads();
        bf16x8 a[4], bh[2];
        #pragma unroll
        for (int s = 0; s < 4; ++s) {
            int r = wr*64 + s*16 + fr;
            a[s] = *(const bf16x8*)&As[r*32 + gsl];
        }
        #pragma unroll
        for (int u = 0; u < 2; ++u) {
            int r = wc*32 + u*16 + fr;
            bh[u] = *(const bf16x8*)&Whs[r*32 + gsl];
        }
        #pragma unroll
        for (int s = 0; s < 4; ++s)
            #pragma unroll
            for (int u = 0; u < 2; ++u)
                acc[s][u] = MFMA(a[s], bh[u], acc[s][u]);
    }
    #pragma unroll
    for (int s = 0; s < 4; ++s) {
        int rb = row0 + wr*64 + s*16 + fg*4;
        #pragma unroll
        for (int u = 0; u < 2; ++u) {
            int c = col0 + wc*32 + u*16 + fr;
            if (c < N) {
                #pragma unroll
                for (int j = 0; j < 4; ++j) {
                    size_t o = (size_t)(rb+j)*ldc + c;
                    C[o] = accum ? (C[o] + acc[s][u][j]) : acc[s][u][j];
                }
            }
        }
    }
}

// ------------- Fused expand GEMM, single-product: bx<nqt -> q GEMM (fp32 out), else GEGLU tile -------------
__global__ __launch_bounds__(256)
void mm_fused2(const ushort* __restrict__ Ag, int lda,
               const ushort* __restrict__ Wqh,
               int Nq, int nqt, float* __restrict__ Qout, int ldq,
               const ushort* __restrict__ W1h, const ushort* __restrict__ W2h,
               ushort* __restrict__ Oh, int ldo, int K)
{
    __shared__ ushort As[128*32];
    __shared__ ushort Xs[2][64*32];
    int tid = threadIdx.x;
    int lane = tid & 63, wid = tid >> 6;
    int bx, by; xcd_swz(gridDim.x, gridDim.y, bx, by);
    int row0 = by*128;
    int wr = wid >> 1, wc = wid & 1;
    int fr = lane & 15, fg = lane >> 4;
    int gsl = (fg ^ ((fr >> 1) & 3)) * 8;
    int sr = tid >> 2, sg0 = tid & 3;
    int g = sg0 ^ ((sr >> 1) & 3);

    if (bx < nqt) {
        int col0 = bx*64;
        int wrow = col0 + sr; if (wrow >= Nq) wrow = Nq - 1;
        ushort8v va[2], vh;
        auto loadk = [&](int k0) {
            #pragma unroll
            for (int i = 0; i < 2; ++i)
                va[i] = *(const ushort8v*)(Ag + (size_t)(row0 + sr + i*64)*lda + k0 + g*8);
            vh = *(const ushort8v*)(Wqh + (size_t)wrow*K + k0 + g*8);
        };
        f32x4 acc[4][2] = {};
        loadk(0);
        for (int k0 = 0; k0 < K; k0 += 32) {
            __syncthreads();
            #pragma unroll
            for (int i = 0; i < 2; ++i)
                *(ushort8v*)&As[(sr + i*64)*32 + sg0*8] = va[i];
            *(ushort8v*)&Xs[0][sr*32 + sg0*8] = vh;
            if (k0 + 32 < K) loadk(k0 + 32);
            __syncthreads();
            bf16x8 a[4], bh[2];
            #pragma unroll
            for (int s = 0; s < 4; ++s) {
                int r = wr*64 + s*16 + fr;
                a[s] = *(const bf16x8*)&As[r*32 + gsl];
            }
            #pragma unroll
            for (int u = 0; u < 2; ++u) {
                int r = wc*32 + u*16 + fr;
                bh[u] = *(const bf16x8*)&Xs[0][r*32 + gsl];
            }
            #pragma unroll
            for (int s = 0; s < 4; ++s)
                #pragma unroll
                for (int u = 0; u < 2; ++u)
                    acc[s][u] = MFMA(a[s], bh[u], acc[s][u]);
        }
        #pragma unroll
        for (int s = 0; s < 4; ++s) {
            int rb = row0 + wr*64 + s*16 + fg*4;
            #pragma unroll
            for (int u = 0; u < 2; ++u) {
                int c = col0 + wc*32 + u*16 + fr;
                if (c < Nq) {
                    #pragma unroll
                    for (int j = 0; j < 4; ++j)
                        Qout[(size_t)(rb+j)*ldq + c] = acc[s][u][j];
                }
            }
        }
    } else {
        int col0 = (bx - nqt)*64;
        ushort8v va[2], vw0, vw2;
        auto loadk = [&](int k0) {
            #pragma unroll
            for (int i = 0; i < 2; ++i)
                va[i] = *(const ushort8v*)(Ag + (size_t)(row0 + sr + i*64)*lda + k0 + g*8);
            size_t wro = (size_t)(col0 + sr)*K + k0 + g*8;
            vw0 = *(const ushort8v*)(W1h + wro);
            vw2 = *(const ushort8v*)(W2h + wro);
        };
        f32x4 acc1[4][2] = {}, acc2[4][2] = {};
        loadk(0);
        for (int k0 = 0; k0 < K; k0 += 32) {
            __syncthreads();
            #pragma unroll
            for (int i = 0; i < 2; ++i)
                *(ushort8v*)&As[(sr + i*64)*32 + sg0*8] = va[i];
            {
                int o = sr*32 + sg0*8;
                *(ushort8v*)&Xs[0][o] = vw0;
                *(ushort8v*)&Xs[1][o] = vw2;
            }
            if (k0 + 32 < K) loadk(k0 + 32);
            __syncthreads();
            bf16x8 a[4], b1[2], b2[2];
            #pragma unroll
            for (int s = 0; s < 4; ++s) {
                int r = wr*64 + s*16 + fr;
                a[s] = *(const bf16x8*)&As[r*32 + gsl];
            }
            #pragma unroll
            for (int u = 0; u < 2; ++u) {
                int r = wc*32 + u*16 + fr;
                b1[u] = *(const bf16x8*)&Xs[0][r*32 + gsl];
                b2[u] = *(const bf16x8*)&Xs[1][r*32 + gsl];
            }
            #pragma unroll
            for (int s = 0; s < 4; ++s)
                #pragma unroll
                for (int u = 0; u < 2; ++u) {
                    acc1[s][u] = MFMA(a[s], b1[u], acc1[s][u]);
                    acc2[s][u] = MFMA(a[s], b2[u], acc2[s][u]);
                }
        }
        #pragma unroll
        for (int s = 0; s < 4; ++s) {
            int rb = row0 + wr*64 + s*16 + fg*4;
            #pragma unroll
            for (int u = 0; u < 2; ++u) {
                int c = col0 + wc*32 + u*16 + fr;
                #pragma unroll
                for (int j = 0; j < 4; ++j) {
                    float gg = acc1[s][u][j] * gelu_f(acc2[s][u][j]);
                    Oh[(size_t)(rb+j)*ldo + c] = f2b(gg);
                }
            }
        }
    }
}

// ------------- batched pk GEMM (2-product, precomputed once): P12[z] = ptp @ Wkv[z]^T -------------
__global__ __launch_bounds__(256)
void pk_mm(const ushort* __restrict__ A,
           const ushort* __restrict__ Wh_, const ushort* __restrict__ Wl_,
           float* __restrict__ P12)
{
    __shared__ ushort Ah[64][72], Wh[64][72], Wl[64][72];
    int tid = threadIdx.x;
    int z = blockIdx.z, blk = z >> 1, half = z & 1;
    int row0 = blockIdx.y*64, col0 = blockIdx.x*64;
    int srow = tid >> 3, sseg = (tid & 7) * 8;
    int wid = tid >> 6, lane = tid & 63;
    int wr = wid >> 1, wc = wid & 1;
    int fr = lane & 15, fg = lane >> 4;
    const ushort* Wbh = Wh_ + (size_t)blk*816*384 + half*192;
    const ushort* Wbl = Wl_ + (size_t)blk*816*384 + half*192;
    float* C = P12 + (size_t)z*128*816;
    f32x4 acc[2][2] = {};
    for (int k0 = 0; k0 < 192; k0 += 64) {
        ushort8v va[2], vc[2], vd[2];
        #pragma unroll
        for (int p = 0; p < 2; ++p) {
            int r = p*32 + srow;
            int wrow = col0 + r; if (wrow >= 816) wrow = 815;
            int gk = k0 + sseg;
            va[p] = *(const ushort8v*)(A + (size_t)(row0 + r)*192 + gk);
            vc[p] = *(const ushort8v*)(Wbh + (size_t)wrow*384 + gk);
            vd[p] = *(const ushort8v*)(Wbl + (size_t)wrow*384 + gk);
        }
        __syncthreads();
        #pragma unroll
        for (int p = 0; p < 2; ++p) {
            int r = p*32 + srow;
            *(ushort8v*)&Ah[r][sseg] = va[p];
            *(ushort8v*)&Wh[r][sseg] = vc[p];
            *(ushort8v*)&Wl[r][sseg] = vd[p];
        }
        __syncthreads();
        #pragma unroll
        for (int kk = 0; kk < 64; kk += 32) {
            bf16x8 a[2], b_h[2], b_l[2];
            #pragma unroll
            for (int s = 0; s < 2; ++s) {
                a[s]   = *(const bf16x8*)&Ah[wr*32 + s*16 + fr][kk + fg*8];
                b_h[s] = *(const bf16x8*)&Wh[wc*32 + s*16 + fr][kk + fg*8];
                b_l[s] = *(const bf16x8*)&Wl[wc*32 + s*16 + fr][kk + fg*8];
            }
            #pragma unroll
            for (int s = 0; s < 2; ++s)
                #pragma unroll
                for (int u = 0; u < 2; ++u)
                    acc[s][u] = MFMA(a[s], b_h[u], acc[s][u]);
            #pragma unroll
            for (int s = 0; s < 2; ++s)
                #pragma unroll
                for (int u = 0; u < 2; ++u)
                    acc[s][u] = MFMA(a[s], b_l[u], acc[s][u]);
        }
        __syncthreads();
    }
    #pragma unroll
    for (int s = 0; s < 2; ++s) {
        int r = row0 + wr*32 + s*16 + fg*4;
        #pragma unroll
        for (int u = 0; u < 2; ++u) {
            int c = col0 + wc*32 + u*16 + fr;
            if (c < 816) {
                #pragma unroll
                for (int j = 0; j < 4; ++j)
                    C[(size_t)(r+j)*816 + c] = acc[s][u][j];
            }
        }
    }
}

// ------------- MFMA batched PV v2: 64x128 block, wave 64x32, T14 pipelined -------------
// XCD swizzle: all blocks of one batch (same z) share V/P panels -> same XCD.
__global__ __launch_bounds__(256)
void pv2(const ushort* __restrict__ P, int ldp, long sP,
         const ushort* __restrict__ V, int ldv, long sV,
         ushort* __restrict__ Oh, int ldo, long sO,
         int Mrows, int K, int Kv)
{
    __shared__ ushort Ps[64][40];
    __shared__ ushort Vs[128*32];
    int L = blockIdx.x + gridDim.x*(blockIdx.y + gridDim.y*blockIdx.z);
    int gz = gridDim.z;
    int zz = L % gz;                    // gz=128 (multiple of 8) -> same zz => same XCD
    int rest = L / gz;
    int bx = rest % gridDim.x;
    int byy = rest / gridDim.x;
    const ushort* Pb = P + (size_t)zz * sP;
    const ushort* Vb = V + (size_t)zz * sV;
    ushort* Ohb = Oh + (size_t)zz * sO;
    int tid = threadIdx.x;
    int row0 = byy*64, col0 = bx*128;
    int wid = tid >> 6, lane = tid & 63;
    int fr = lane & 15, fg = lane >> 4;
    int prow = tid >> 2, pseg = (tid & 3) * 8;
    int vk = tid & 31, vcb = (tid >> 5) * 8;

    ushort8v pv_, vv[2];
    auto loadk = [&](int k0) {
        pv_ = (ushort8v){0,0,0,0,0,0,0,0};
        int grow = row0 + prow;
        if (grow < Mrows)
            pv_ = *(const ushort8v*)(Pb + (size_t)grow*ldp + k0 + pseg);
        vv[0] = (ushort8v){0,0,0,0,0,0,0,0};
        vv[1] = (ushort8v){0,0,0,0,0,0,0,0};
        int gk = k0 + vk;
        if (gk < Kv) {
            #pragma unroll
            for (int i = 0; i < 2; ++i)
                vv[i] = *(const ushort8v*)(Vb + (size_t)gk*ldv + col0 + vcb + i*64);
        }
    };

    f32x4 acc[4][2] = {};
    loadk(0);
    for (int k0 = 0; k0 < K; k0 += 32) {
        __syncthreads();
        *(ushort8v*)&Ps[prow][pseg] = pv_;
        #pragma unroll
        for (int i = 0; i < 2; ++i) {
            #pragma unroll
            for (int e = 0; e < 8; ++e) {
                int c = vcb + i*64 + e;
                Vs[c*32 + (vk & 7) + 8*((vk >> 3) ^ ((c >> 3) & 3))] = vv[i][e];
            }
        }
        if (k0 + 32 < K) loadk(k0 + 32);
        __syncthreads();
        bf16x8 a[4], b[2];
        #pragma unroll
        for (int s = 0; s < 4; ++s)
            a[s] = *(const bf16x8*)&Ps[s*16 + fr][fg*8];
        #pragma unroll
        for (int u = 0; u < 2; ++u) {
            int c = wid*32 + u*16 + fr;
            b[u] = *(const bf16x8*)&Vs[c*32 + 8*(fg ^ ((c >> 3) & 3))];
        }
        #pragma unroll
        for (int s = 0; s < 4; ++s)
            #pragma unroll
            for (int u = 0; u < 2; ++u)
                acc[s][u] = MFMA(a[s], b[u], acc[s][u]);
    }
    #pragma unroll
    for (int s = 0; s < 4; ++s) {
        int rbase = row0 + s*16 + fg*4;
        #pragma unroll
        for (int u = 0; u < 2; ++u) {
            int c = col0 + wid*32 + u*16 + fr;
            #pragma unroll
            for (int j = 0; j < 4; ++j) {
                int r = rbase + j;
                if (r < Mrows)
                    Ohb[(size_t)r*ldo + c] = f2b(acc[s][u][j]);
            }
        }
    }
}

// ------------- MFMA attention scores + softmax -> normalized P (bf16) -------------
// grid (2, B_): row slab (64 rows), batch. Score/softmax logic identical to the
// round-21 verified fused kernel; standalone (no col-tile redundancy).
template<int NK, int CAUSAL>
__global__ __launch_bounds__(256)
void attn_score_mfma(const float* __restrict__ Q, int ldq, long sQ,
                     const float* __restrict__ Kf, int ldk, int koff, long sK,
                     ushort* __restrict__ P,
                     const float* __restrict__ bm, int blk, int Kv)
{
    constexpr int NKF = NK / 16;
    __shared__ ushort Qs[64*72];
    __shared__ ushort Ks[NK*72];
    int slab = blockIdx.x;
    int zz = blockIdx.y;
    int row0 = slab*64;
    int tid = threadIdx.x;
    int wv = tid >> 6, lane = tid & 63;
    int fr = lane & 15, fg = lane >> 4;

    const float scale = 0.14433756729740643f;
    float sp = 0.f;
    if (CAUSAL) { float bmv = bm[blk]; sp = (bmv > 20.f) ? bmv : log1pf(expf(bmv)); }

    const float* Qb = Q + (size_t)zz * sQ;
    for (int idx = tid; idx < 64*64; idx += 256) {
        int r = idx >> 6, c = idx & 63;
        int grow = row0 + r; if (grow >= S_) grow = S_ - 1;
        ushort v = 0;
        if (c < 48) v = f2b(Qb[(size_t)grow*ldq + c]);
        Qs[r*72 + c] = v;
    }
    const float* Kb = Kf + (size_t)zz*sK + koff;
    for (int idx = tid; idx < NK*64; idx += 256) {
        int j = idx >> 6, c = idx & 63;
        ushort v = 0;
        if (c < 48 && j < Kv) v = f2b(Kb[(size_t)j*ldk + c]);
        Ks[j*72 + c] = v;
    }
    __syncthreads();

    f32x4 sacc[NKF];
    #pragma unroll
    for (int kf = 0; kf < NKF; ++kf) sacc[kf] = (f32x4){0.f,0.f,0.f,0.f};
    bf16x8 aq0 = *(const bf16x8*)&Qs[(wv*16 + fr)*72 +  0 + fg*8];
    bf16x8 aq1 = *(const bf16x8*)&Qs[(wv*16 + fr)*72 + 32 + fg*8];
    #pragma unroll
    for (int kf = 0; kf < NKF; ++kf) {
        bf16x8 bk0 = *(const bf16x8*)&Ks[(kf*16 + fr)*72 +  0 + fg*8];
        bf16x8 bk1 = *(const bf16x8*)&Ks[(kf*16 + fr)*72 + 32 + fg*8];
        sacc[kf] = MFMA(aq0, bk0, sacc[kf]);
        sacc[kf] = MFMA(aq1, bk1, sacc[kf]);
    }
    #pragma unroll
    for (int j = 0; j < 4; ++j) {
        int i = row0 + wv*16 + fg*4 + j;
        float m = -1e30f;
        #pragma unroll
        for (int kf = 0; kf < NKF; ++kf) {
            int key = kf*16 + fr;
            float s = sacc[kf][j] * scale;
            if (CAUSAL) s = (key <= i) ? (s + sp*(float)(key - i)) : -1e30f;
            sacc[kf][j] = s;
            m = fmaxf(m, s);
        }
        #pragma unroll
        for (int off = 1; off < 16; off <<= 1) m = fmaxf(m, __shfl_xor(m, off));
        float sum = 0.f;
        #pragma unroll
        for (int kf = 0; kf < NKF; ++kf) {
            float p = __expf(sacc[kf][j] - m);
            sacc[kf][j] = p;
            sum += p;
        }
        #pragma unroll
        for (int off = 1; off < 16; off <<= 1) sum += __shfl_xor(sum, off);
        float inv = 1.f / sum;
        if (i < S_) {
            ushort* prow = P + ((size_t)(zz*S_) + i)*NK;
            #pragma unroll
            for (int kf = 0; kf < NKF; ++kf)
                prow[kf*16 + fr] = f2b(sacc[kf][j] * inv);
        }
    }
}

// ------------- gather pk rows -> k2 (fp32), geglu'd values gv (bf16) -------------
__global__ __launch_bounds__(256)
void pk_gather(const int* __restrict__ pts, const float* __restrict__ P12, int blk,
               float* __restrict__ k2, ushort* __restrict__ gv)
{
    int pair = blockIdx.x*4 + (threadIdx.x >> 6);
    int lane = threadIdx.x & 63;
    const float* P1 = P12 + (size_t)(blk*2 + 0)*128*816;
    const float* P2 = P12 + (size_t)(blk*2 + 1)*128*816;
    int t0 = pts[2*pair], t1 = pts[2*pair+1];
    const float* a = P1 + (size_t)t0*816;
    const float* c = P2 + (size_t)t1*816;
    if (lane < QK_) k2[(size_t)pair*QK_ + lane] = a[lane] + c[lane];
    #pragma unroll
    for (int t = 0; t < 6; ++t) {
        int i = lane + 64*t;
        float lin = a[48 + i] + c[48 + i];
        float pre = a[432 + i] + c[432 + i];
        gv[(size_t)pair*D_ + i] = f2b(lin * gelu_f(pre));
    }
}

// all layers at once: blockIdx.y = layer
__global__ __launch_bounds__(256)
void pk_gather_all(const int* __restrict__ pts, const float* __restrict__ P12,
                   float* __restrict__ k2, ushort* __restrict__ gv)
{
    int pair = blockIdx.x*4 + (threadIdx.x >> 6);
    int lane = threadIdx.x & 63;
    int blk = blockIdx.y;
    const float* P1 = P12 + (size_t)(blk*2 + 0)*128*816;
    const float* P2 = P12 + (size_t)(blk*2 + 1)*128*816;
    float* k2b = k2 + (size_t)blk*B_*NPTS_*QK_;
    ushort* gvb = gv + (size_t)blk*B_*NPTS_*D_;
    int t0 = pts[2*pair], t1 = pts[2*pair+1];
    const float* a = P1 + (size_t)t0*816;
    const float* c = P2 + (size_t)t1*816;
    if (lane < QK_) k2b[(size_t)pair*QK_ + lane] = a[lane] + c[lane];
    #pragma unroll
    for (int t = 0; t < 6; ++t) {
        int i = lane + 64*t;
        float lin = a[48 + i] + c[48 + i];
        float pre = a[432 + i] + c[432 + i];
        gvb[(size_t)pair*D_ + i] = f2b(lin * gelu_f(pre));
    }
}

extern "C" void kernel_launch(void* const* d_in, const int* in_sizes, int n_in,
                              void* d_out, int out_size, void* d_ws, size_t ws_size,
                              hipStream_t stream)
{
    const int*   qtok  = (const int*)d_in[0];
    const int*   pts   = (const int*)d_in[1];
    const float* emb   = (const float*)d_in[2];
    const float* ptemb = (const float*)d_in[3];
    const float* normw = (const float*)d_in[4];
    const float* outw  = (const float*)d_in[5];
    const float* ln1   = (const float*)d_in[6];
    const float* expand= (const float*)d_in[7];
    const float* proj1 = (const float*)d_in[8];
    const float* bm    = (const float*)d_in[9];
    const float* ln2   = (const float*)d_in[10];
    const float* Wq    = (const float*)d_in[11];
    const float* Wkv   = (const float*)d_in[12];
    const float* proj2 = (const float*)d_in[13];
    float* out = (float*)d_out;

    char* base = (char*)d_ws;
    size_t off = 0;
    auto alloc = [&](size_t bytes){ void* p = base + off; off += (bytes + 255) & ~(size_t)255; return p; };
    float*  h     = (float*) alloc((size_t)M_*D_*4);
    ushort* nh    = (ushort*)alloc((size_t)M_*D_*2);
    float*  qk1   = (float*) alloc((size_t)M_*96*4);     // qr2 aliases
    ushort* gegl  = (ushort*)alloc((size_t)M_*E_*2);     // gloc aliases
    ushort* atb   = (ushort*)alloc((size_t)M_*D_*2);
    ushort* Pbuf  = (ushort*)alloc((size_t)M_*256*2);
    float*  P12   = (float*) alloc((size_t)16*128*816*4);
    ushort* wkvh  = (ushort*)alloc((size_t)NB_*816*384*2);
    ushort* wkvl  = (ushort*)alloc((size_t)NB_*816*384*2);
    ushort* ptp   = (ushort*)alloc((size_t)128*192*2);
    ushort* obh   = (ushort*)alloc((size_t)NTOK_*D_*2);
    ushort* obl   = (ushort*)alloc((size_t)NTOK_*D_*2);

    // weight buffer (hi only): all 8 layers if workspace allows, else single-layer
    size_t rem = (ws_size > off) ? (ws_size - off) : 0;
    bool fits8 = rem >= ((size_t)NB_ * WTOT * 2
                         + (size_t)B_*NPTS_*D_*2 + (size_t)B_*NPTS_*QK_*4 + 4096);
    int nlay = fits8 ? NB_ : 1;
    ushort* wbh = (ushort*)alloc((size_t)nlay*WTOT*2);
    size_t wstride = fits8 ? (size_t)WTOT : 0;

    // pk-gather buffers: all 8 layers if workspace allows (hoist), else per-layer
    size_t gv_l = (size_t)B_*NPTS_*D_;   // elements (ushort)
    size_t k2_l = (size_t)B_*NPTS_*QK_;  // elements (float)
    size_t rem2 = (ws_size > off) ? (ws_size - off) : 0;
    bool fitsPK = rem2 >= ((size_t)NB_*gv_l*2 + (size_t)NB_*k2_l*4 + 4096);
    int play = fitsPK ? NB_ : 1;
    ushort* gvB = (ushort*)alloc((size_t)play*gv_l*2);
    float*  k2B = (float*) alloc((size_t)play*k2_l*4);
    size_t gvs = fitsPK ? gv_l : 0;
    size_t k2s = fitsPK ? k2_l : 0;

    float*  qr2   = qk1;
    ushort* gloc  = gegl;

    const size_t oWE = 0;
    const size_t oP1 = WE_SZ;
    const size_t oWQ = WE_SZ + P1_SZ;
    const size_t oP2 = WE_SZ + P1_SZ + WQ_SZ;

    x_init<<<M_/4, 256, 0, stream>>>(qtok, emb, normw, h, M_);
    pconv<<<(128*192 + 255)/256, 256, 0, stream>>>(ptemb, ptp);
    wconv1<<<(NB_*816*384 + 255)/256, 256, 0, stream>>>(Wkv, NB_*816*384, wkvh, wkvl);
    pk_mm<<<dim3(13, 2, 16), 256, 0, stream>>>(ptp, wkvh, wkvl, P12);
    if (fits8)
        wconv_all_hi<<<dim3((WTOT+255)/256, NB_), 256, 0, stream>>>(
            expand, proj1, Wq, proj2, wbh);
    if (fitsPK)
        pk_gather_all<<<dim3(B_*NPTS_/4, NB_), 256, 0, stream>>>(pts, P12, k2B, gvB);

    for (int blk = 0; blk < NB_; ++blk) {
        if (!fits8)
            wconv_hi<<<(WTOT+255)/256, 256, 0, stream>>>(
                expand + (size_t)blk*WE_SZ, proj1 + (size_t)blk*P1_SZ,
                Wq + (size_t)blk*WQ_SZ, proj2 + (size_t)blk*P2_SZ, wbh);
        const ushort* Lh = wbh + wstride*blk;
        ushort* gv = gvB + gvs*blk;
        float*  k2 = k2B + k2s*blk;

        ln_rows<<<M_/4, 256, 0, stream>>>(h, ln1 + blk*D_, nh, M_);
        // fused: qk (N=96 -> 2 tiles) + geglu768 (12 tiles)
        mm_fused2<<<dim3(14, M_/128), 256, 0, stream>>>(nh, D_,
            Lh + oWE, 96, 2, qk1, 96,
            Lh + oWE + (size_t)96*D_, Lh + oWE + (size_t)864*D_,
            gegl, E_, D_);
        // MFMA scores + softmax (causal + linear bias), keys padded 100->128
        attn_score_mfma<128,1><<<dim3(2, B_), 256, 0, stream>>>(
            qk1, 96, (long)S_*96,
            qk1, 96, 48, (long)S_*96,
            Pbuf, bm, blk, S_);
        pv2<<<dim3(3,2,B_), 256, 0, stream>>>(Pbuf, 128, (long)S_*128,
            gegl + LOCAL_, E_, (long)S_*E_,
            atb, D_, (long)S_*D_, S_, 128, S_);
        // h += [geglu_local | attn] @ W_p1^T
        mm_bt2<<<dim3(6, M_/128), 256, 0, stream>>>(gegl, E_, D_, atb, D_,
            Lh + oP1, h, D_, D_, E_, 1);

        ln_rows<<<M_/4, 256, 0, stream>>>(h, ln2 + blk*D_, nh, M_);
        // fused: qr2 (N=48 -> 1 tile) + geglu384 (6 tiles)
        mm_fused2<<<dim3(7, M_/128), 256, 0, stream>>>(nh, D_,
            Lh + oWQ, 48, 1, qr2, 48,
            Lh + oWQ + (size_t)48*D_, Lh + oWQ + (size_t)432*D_,
            gloc, D_, D_);
        // pk path (P12 precomputed; gather hoisted if it fits)
        if (!fitsPK)
            pk_gather<<<B_*NPTS_/4, 256, 0, stream>>>(pts, P12, blk, k2, gv);
        // MFMA scores + softmax (no mask), 256 keys
        attn_score_mfma<256,0><<<dim3(2, B_), 256, 0, stream>>>(
            qr2, 48, (long)S_*48,
            k2, 48, 0, (long)NPTS_*48,
            Pbuf, bm, blk, NPTS_);
        pv2<<<dim3(3,2,B_), 256, 0, stream>>>(Pbuf, 256, (long)S_*256,
            gv, D_, (long)NPTS_*D_,
            atb, D_, (long)S_*D_, S_, 256, 256);
        // h += [g_local | attn2] @ W_p2^T
        mm_bt2<<<dim3(6, M_/128), 256, 0, stream>>>(gloc, D_, D_, atb, D_,
            Lh + oP2, h, D_, D_, E_, 1);
    }

    ln_rows<<<M_/4, 256, 0, stream>>>(h, normw, nh, M_);
    wconv1<<<(NTOK_*D_ + 255)/256, 256, 0, stream>>>(outw, NTOK_*D_, obh, obl);
    mm_bt64<<<dim3(2, M_/64), 256, 0, stream>>>(nh, D_, D_, nh, D_,
        obh, obl, out, NTOK_, NTOK_, D_, 0);
}

// Round 26
// 1618.833 us; speedup vs baseline: 1.0240x; 1.0166x over previous
//
#include <hip/hip_runtime.h>
#include <hip/hip_bf16.h>
#include <math.h>

#define B_    128
#define S_    100
#define D_    384
#define QK_   48
#define E_    768
#define LOCAL_ 384
#define NB_   8
#define NTOK_ 100
#define NPTS_ 256
#define M_    (B_*S_)   // 12800

typedef unsigned short ushort;
typedef __attribute__((ext_vector_type(8))) short  bf16x8;
typedef __attribute__((ext_vector_type(8))) unsigned short ushort8v;
typedef __attribute__((ext_vector_type(4))) float  f32x4;

#define MFMA(a,b,c) __builtin_amdgcn_mfma_f32_16x16x32_bf16(a,b,c,0,0,0)

// fast GELU (tanh form): max |diff vs exact erf-GELU| ~3e-4, well under tolerance
static __device__ __forceinline__ float gelu_f(float x) {
    float y = 1.5957691216057308f * (x + 0.044715f * x * x * x);
    float e = __expf(y);
    float t = 1.0f - 2.0f / (e + 1.0f);
    return 0.5f * x * (1.0f + t);
}
static __device__ __forceinline__ ushort f2b(float f) {
    union { float f; unsigned u; } x; x.f = f;
    unsigned r = x.u + 0x7FFFu + ((x.u >> 16) & 1u);
    return (ushort)(r >> 16);
}
static __device__ __forceinline__ float b2f(ushort u) {
    union { unsigned u; float f; } x; x.u = ((unsigned)u) << 16;
    return x.f;
}

// XCD-locality swizzle: group row-panels (by) in chunks of 8 so all col-tiles (bx)
// of one panel land on the same XCD.
static __device__ __forceinline__ void xcd_swz(int xn, int gy, int& bx, int& by) {
    int L = blockIdx.x + xn * blockIdx.y;
    int gmain = (gy & ~7) * xn;
    if (L < gmain) {
        int grp = L / (8 * xn);
        int r = L % (8 * xn);
        bx = r >> 3;
        by = grp * 8 + (r & 7);
    } else {
        int Lp = L - gmain;
        int tail = gy & 7;
        by = (gy & ~7) + (Lp % tail);
        bx = Lp / tail;
    }
}

// ---------------- LayerNorm: fp32 in -> bf16 out ----------------
__global__ __launch_bounds__(256)
void ln_rows(const float* __restrict__ X, const float* __restrict__ w,
             ushort* __restrict__ Y, int nrows)
{
    int row = blockIdx.x * 4 + (threadIdx.x >> 6);
    if (row >= nrows) return;
    int lane = threadIdx.x & 63;
    const float* x = X + (size_t)row * D_;
    float v[6]; float s = 0.f;
    #pragma unroll
    for (int t = 0; t < 6; ++t) { v[t] = x[lane + 64*t]; s += v[t]; }
    #pragma unroll
    for (int off = 32; off; off >>= 1) s += __shfl_xor(s, off);
    float mu = s * (1.f/(float)D_);
    float q = 0.f;
    #pragma unroll
    for (int t = 0; t < 6; ++t) { float d = v[t]-mu; q += d*d; }
    #pragma unroll
    for (int off = 32; off; off >>= 1) q += __shfl_xor(q, off);
    float rs = rsqrtf(q * (1.f/(float)D_) + 1e-5f);
    #pragma unroll
    for (int t = 0; t < 6; ++t)
        Y[(size_t)row*D_ + lane + 64*t] = f2b((v[t]-mu)*rs*w[lane + 64*t]);
}

// ------------- gather emb[q] + LayerNorm -> fp32 h -------------
__global__ __launch_bounds__(256)
void x_init(const int* __restrict__ qtok, const float* __restrict__ emb,
            const float* __restrict__ w, float* __restrict__ Y, int nrows)
{
    int row = blockIdx.x * 4 + (threadIdx.x >> 6);
    if (row >= nrows) return;
    int lane = threadIdx.x & 63;
    const float* x = emb + (size_t)qtok[row] * D_;
    float v[6]; float s = 0.f;
    #pragma unroll
    for (int t = 0; t < 6; ++t) { v[t] = x[lane + 64*t]; s += v[t]; }
    #pragma unroll
    for (int off = 32; off; off >>= 1) s += __shfl_xor(s, off);
    float mu = s * (1.f/(float)D_);
    float q = 0.f;
    #pragma unroll
    for (int t = 0; t < 6; ++t) { float d = v[t]-mu; q += d*d; }
    #pragma unroll
    for (int off = 32; off; off >>= 1) q += __shfl_xor(q, off);
    float rs = rsqrtf(q * (1.f/(float)D_) + 1e-5f);
    float* y = Y + (size_t)row * D_;
    #pragma unroll
    for (int t = 0; t < 6; ++t) y[lane + 64*t] = (v[t]-mu)*rs*w[lane + 64*t];
}

// ------------- weight conversion -------------
#define WE_SZ  (1632*384)
#define P1_SZ  (384*768)
#define WQ_SZ  (816*384)
#define P2_SZ  (384*768)
#define WTOT   (WE_SZ + P1_SZ + WQ_SZ + P2_SZ)

static __device__ __forceinline__ void wsplit(float v, ushort* wh, ushort* wl, size_t o) {
    ushort h = f2b(v);
    wh[o] = h; wl[o] = f2b(v - b2f(h));
}

// all layers at once, hi only (plain bf16 weights): blockIdx.y = layer
__global__ __launch_bounds__(256)
void wconv_all_hi(const float* __restrict__ expand, const float* __restrict__ proj1,
                  const float* __restrict__ wq, const float* __restrict__ proj2,
                  ushort* __restrict__ wh)
{
    int i = blockIdx.x*256 + threadIdx.x;
    if (i >= WTOT) return;
    int blk = blockIdx.y;
    float v;
    if (i < WE_SZ) v = expand[(size_t)blk*WE_SZ + i];
    else if (i < WE_SZ+P1_SZ) v = proj1[(size_t)blk*P1_SZ + (i - WE_SZ)];
    else if (i < WE_SZ+P1_SZ+WQ_SZ) v = wq[(size_t)blk*WQ_SZ + (i - WE_SZ - P1_SZ)];
    else v = proj2[(size_t)blk*P2_SZ + (i - WE_SZ - P1_SZ - WQ_SZ)];
    wh[(size_t)blk*WTOT + i] = f2b(v);
}

__global__ __launch_bounds__(256)
void wconv_hi(const float* __restrict__ we, const float* __restrict__ p1,
              const float* __restrict__ wq, const float* __restrict__ p2,
              ushort* __restrict__ wh)
{
    int i = blockIdx.x*256 + threadIdx.x;
    if (i >= WTOT) return;
    float v;
    if (i < WE_SZ) v = we[i];
    else if (i < WE_SZ+P1_SZ) v = p1[i - WE_SZ];
    else if (i < WE_SZ+P1_SZ+WQ_SZ) v = wq[i - WE_SZ - P1_SZ];
    else v = p2[i - WE_SZ - P1_SZ - WQ_SZ];
    wh[i] = f2b(v);
}

__global__ __launch_bounds__(256)
void wconv1(const float* __restrict__ src, int n,
            ushort* __restrict__ wh, ushort* __restrict__ wl)
{
    int i = blockIdx.x*256 + threadIdx.x;
    if (i >= n) return;
    wsplit(src[i], wh, wl, i);
}

// ------------- pt_emb -> bf16, padded to 128 rows -------------
__global__ __launch_bounds__(256)
void pconv(const float* __restrict__ src, ushort* __restrict__ dst)
{
    int i = blockIdx.x*256 + threadIdx.x;
    if (i >= 128*192) return;
    int r = i / 192;
    dst[i] = (r < NTOK_) ? f2b(src[i]) : 0;
}

// ------------- MFMA 2-product GEMM, 64x64 block (final out GEMM, accuracy-critical) -------------
__global__ __launch_bounds__(256)
void mm_bt64(const ushort* __restrict__ A1, int lda1, int K1,
             const ushort* __restrict__ A2, int lda2,
             const ushort* __restrict__ Wgh, const ushort* __restrict__ Wgl,
             float* __restrict__ C, int ldc, int N, int K, int accum)
{
    __shared__ ushort Ah[64][72], Wh[64][72], Wl[64][72];
    int tid = threadIdx.x;
    int row0 = blockIdx.y*64, col0 = blockIdx.x*64;
    int srow = tid >> 3;
    int sseg = (tid & 7) * 8;
    int wid = tid >> 6, lane = tid & 63;
    int wr = wid >> 1, wc = wid & 1;
    int fr = lane & 15, fg = lane >> 4;
    f32x4 acc[2][2] = {};
    for (int k0 = 0; k0 < K; k0 += 64) {
        ushort8v va[2], vc[2], vd[2];
        #pragma unroll
        for (int p = 0; p < 2; ++p) {
            int r = p*32 + srow;
            int arow = row0 + r;
            int wrow = col0 + r;
            int gk = k0 + sseg;
            if (gk < K1) va[p] = *(const ushort8v*)(A1 + (size_t)arow*lda1 + gk);
            else         va[p] = *(const ushort8v*)(A2 + (size_t)arow*lda2 + (gk-K1));
            if (wrow >= N) wrow = N - 1;
            vc[p] = *(const ushort8v*)(Wgh + (size_t)wrow*K + gk);
            vd[p] = *(const ushort8v*)(Wgl + (size_t)wrow*K + gk);
        }
        __syncthreads();
        #pragma unroll
        for (int p = 0; p < 2; ++p) {
            int r = p*32 + srow;
            *(ushort8v*)&Ah[r][sseg] = va[p];
            *(ushort8v*)&Wh[r][sseg] = vc[p];
            *(ushort8v*)&Wl[r][sseg] = vd[p];
        }
        __syncthreads();
        #pragma unroll
        for (int kk = 0; kk < 64; kk += 32) {
            bf16x8 a[2], b_h[2], b_l[2];
            #pragma unroll
            for (int s = 0; s < 2; ++s) {
                a[s]   = *(const bf16x8*)&Ah[wr*32 + s*16 + fr][kk + fg*8];
                b_h[s] = *(const bf16x8*)&Wh[wc*32 + s*16 + fr][kk + fg*8];
                b_l[s] = *(const bf16x8*)&Wl[wc*32 + s*16 + fr][kk + fg*8];
            }
            #pragma unroll
            for (int s = 0; s < 2; ++s)
                #pragma unroll
                for (int u = 0; u < 2; ++u)
                    acc[s][u] = MFMA(a[s], b_h[u], acc[s][u]);
            #pragma unroll
            for (int s = 0; s < 2; ++s)
                #pragma unroll
                for (int u = 0; u < 2; ++u)
                    acc[s][u] = MFMA(a[s], b_l[u], acc[s][u]);
        }
        __syncthreads();
    }
    #pragma unroll
    for (int s = 0; s < 2; ++s) {
        int r = row0 + wr*32 + s*16 + fg*4;
        #pragma unroll
        for (int u = 0; u < 2; ++u) {
            int c = col0 + wc*32 + u*16 + fr;
            if (c < N) {
                #pragma unroll
                for (int j = 0; j < 4; ++j) {
                    size_t o = (size_t)(r+j)*ldc + c;
                    C[o] = accum ? (C[o] + acc[s][u][j]) : acc[s][u][j];
                }
            }
        }
    }
}

// ------------- MFMA single-product GEMM, 128x64 block, wave 64x32, BK=64, T14 pipelined -------------
// K, K1 multiples of 64.
__global__ __launch_bounds__(256)
void mm_bt2(const ushort* __restrict__ A1, int lda1, int K1,
            const ushort* __restrict__ A2, int lda2,
            const ushort* __restrict__ Wgh,
            float* __restrict__ C, int ldc, int N, int K, int accum)
{
    __shared__ ushort As[128*64], Whs[64*64];
    int tid = threadIdx.x;
    int lane = tid & 63, wid = tid >> 6;
    int bx, by; xcd_swz(gridDim.x, gridDim.y, bx, by);
    int row0 = by*128, col0 = bx*64;
    int wr = wid >> 1, wc = wid & 1;
    int fr = lane & 15, fg = lane >> 4;
    int gsl = (fg ^ ((fr >> 1) & 3)) * 8;
    int sr = tid >> 2, sg0 = tid & 3;
    int gA[2];
    gA[0] = sg0 ^ ((sr >> 1) & 3);          // row sr (and sr+64: same parity bits)
    gA[1] = gA[0];
    int wrow = col0 + sr; if (wrow >= N) wrow = N - 1;

    ushort8v va[2][2], vh[2];
    auto loadk = [&](int k0) {
        const ushort* Asrc; int lda, kk;
        if (k0 < K1) { Asrc = A1; lda = lda1; kk = k0; }
        else         { Asrc = A2; lda = lda2; kk = k0 - K1; }
        #pragma unroll
        for (int i = 0; i < 2; ++i) {
            const ushort* rp = Asrc + (size_t)(row0 + sr + i*64)*lda + kk;
            va[i][0] = *(const ushort8v*)(rp +  0 + gA[i]*8);
            va[i][1] = *(const ushort8v*)(rp + 32 + gA[i]*8);
        }
        const ushort* wp = Wgh + (size_t)wrow*K + k0;
        vh[0] = *(const ushort8v*)(wp +  0 + gA[0]*8);
        vh[1] = *(const ushort8v*)(wp + 32 + gA[0]*8);
    };

    int nsteps = K >> 6;
    f32x4 acc[4][2] = {};
    loadk(0);
    for (int t = 0; t < nsteps; ++t) {
        __syncthreads();
        #pragma unroll
        for (int i = 0; i < 2; ++i) {
            int rb = (sr + i*64)*64;
            *(ushort8v*)&As[rb +  0 + sg0*8] = va[i][0];
            *(ushort8v*)&As[rb + 32 + sg0*8] = va[i][1];
        }
        {
            int rb = sr*64;
            *(ushort8v*)&Whs[rb +  0 + sg0*8] = vh[0];
            *(ushort8v*)&Whs[rb + 32 + sg0*8] = vh[1];
        }
        if (t + 1 < nsteps) loadk((t+1)*64);
        __syncthreads();
        #pragma unroll
        for (int kk = 0; kk < 64; kk += 32) {
            bf16x8 a[4], bh[2];
            #pragma unroll
            for (int s = 0; s < 4; ++s) {
                int r = wr*64 + s*16 + fr;
                a[s] = *(const bf16x8*)&As[r*64 + kk + gsl];
            }
            #pragma unroll
            for (int u = 0; u < 2; ++u) {
                int r = wc*32 + u*16 + fr;
                bh[u] = *(const bf16x8*)&Whs[r*64 + kk + gsl];
            }
            #pragma unroll
            for (int s = 0; s < 4; ++s)
                #pragma unroll
                for (int u = 0; u < 2; ++u)
                    acc[s][u] = MFMA(a[s], bh[u], acc[s][u]);
        }
    }
    #pragma unroll
    for (int s = 0; s < 4; ++s) {
        int rb = row0 + wr*64 + s*16 + fg*4;
        #pragma unroll
        for (int u = 0; u < 2; ++u) {
            int c = col0 + wc*32 + u*16 + fr;
            if (c < N) {
                #pragma unroll
                for (int j = 0; j < 4; ++j) {
                    size_t o = (size_t)(rb+j)*ldc + c;
                    C[o] = accum ? (C[o] + acc[s][u][j]) : acc[s][u][j];
                }
            }
        }
    }
}

// ------------- Fused expand GEMM, single-product, BK=64: bx<nqt -> q GEMM (fp32 out), else GEGLU -------------
__global__ __launch_bounds__(256)
void mm_fused2(const ushort* __restrict__ Ag, int lda,
               const ushort* __restrict__ Wqh,
               int Nq, int nqt, float* __restrict__ Qout, int ldq,
               const ushort* __restrict__ W1h, const ushort* __restrict__ W2h,
               ushort* __restrict__ Oh, int ldo, int K)
{
    __shared__ ushort As[128*64];
    __shared__ ushort Xs[2][64*64];
    int tid = threadIdx.x;
    int lane = tid & 63, wid = tid >> 6;
    int bx, by; xcd_swz(gridDim.x, gridDim.y, bx, by);
    int row0 = by*128;
    int wr = wid >> 1, wc = wid & 1;
    int fr = lane & 15, fg = lane >> 4;
    int gsl = (fg ^ ((fr >> 1) & 3)) * 8;
    int sr = tid >> 2, sg0 = tid & 3;
    int gA = sg0 ^ ((sr >> 1) & 3);
    int nsteps = K >> 6;

    if (bx < nqt) {
        int col0 = bx*64;
        int wrow = col0 + sr; if (wrow >= Nq) wrow = Nq - 1;
        ushort8v va[2][2], vh[2];
        auto loadk = [&](int k0) {
            #pragma unroll
            for (int i = 0; i < 2; ++i) {
                const ushort* rp = Ag + (size_t)(row0 + sr + i*64)*lda + k0;
                va[i][0] = *(const ushort8v*)(rp +  0 + gA*8);
                va[i][1] = *(const ushort8v*)(rp + 32 + gA*8);
            }
            const ushort* wp = Wqh + (size_t)wrow*K + k0;
            vh[0] = *(const ushort8v*)(wp +  0 + gA*8);
            vh[1] = *(const ushort8v*)(wp + 32 + gA*8);
        };
        f32x4 acc[4][2] = {};
        loadk(0);
        for (int t = 0; t < nsteps; ++t) {
            __syncthreads();
            #pragma unroll
            for (int i = 0; i < 2; ++i) {
                int rb = (sr + i*64)*64;
                *(ushort8v*)&As[rb +  0 + sg0*8] = va[i][0];
                *(ushort8v*)&As[rb + 32 + sg0*8] = va[i][1];
            }
            {
                int rb = sr*64;
                *(ushort8v*)&Xs[0][rb +  0 + sg0*8] = vh[0];
                *(ushort8v*)&Xs[0][rb + 32 + sg0*8] = vh[1];
            }
            if (t + 1 < nsteps) loadk((t+1)*64);
            __syncthreads();
            #pragma unroll
            for (int kk = 0; kk < 64; kk += 32) {
                bf16x8 a[4], bh[2];
                #pragma unroll
                for (int s = 0; s < 4; ++s) {
                    int r = wr*64 + s*16 + fr;
                    a[s] = *(const bf16x8*)&As[r*64 + kk + gsl];
                }
                #pragma unroll
                for (int u = 0; u < 2; ++u) {
                    int r = wc*32 + u*16 + fr;
                    bh[u] = *(const bf16x8*)&Xs[0][r*64 + kk + gsl];
                }
                #pragma unroll
                for (int s = 0; s < 4; ++s)
                    #pragma unroll
                    for (int u = 0; u < 2; ++u)
                        acc[s][u] = MFMA(a[s], bh[u], acc[s][u]);
            }
        }
        #pragma unroll
        for (int s = 0; s < 4; ++s) {
            int rb = row0 + wr*64 + s*16 + fg*4;
            #pragma unroll
            for (int u = 0; u < 2; ++u) {
                int c = col0 + wc*32 + u*16 + fr;
                if (c < Nq) {
                    #pragma unroll
                    for (int j = 0; j < 4; ++j)
                        Qout[(size_t)(rb+j)*ldq + c] = acc[s][u][j];
                }
            }
        }
    } else {
        int col0 = (bx - nqt)*64;
        ushort8v va[2][2], vw0[2], vw2[2];
        auto loadk = [&](int k0) {
            #pragma unroll
            for (int i = 0; i < 2; ++i) {
                const ushort* rp = Ag + (size_t)(row0 + sr + i*64)*lda + k0;
                va[i][0] = *(const ushort8v*)(rp +  0 + gA*8);
                va[i][1] = *(const ushort8v*)(rp + 32 + gA*8);
            }
            size_t wro = (size_t)(col0 + sr)*K + k0;
            vw0[0] = *(const ushort8v*)(W1h + wro +  0 + gA*8);
            vw0[1] = *(const ushort8v*)(W1h + wro + 32 + gA*8);
            vw2[0] = *(const ushort8v*)(W2h + wro +  0 + gA*8);
            vw2[1] = *(const ushort8v*)(W2h + wro + 32 + gA*8);
        };
        f32x4 acc1[4][2] = {}, acc2[4][2] = {};
        loadk(0);
        for (int t = 0; t < nsteps; ++t) {
            __syncthreads();
            #pragma unroll
            for (int i = 0; i < 2; ++i) {
                int rb = (sr + i*64)*64;
                *(ushort8v*)&As[rb +  0 + sg0*8] = va[i][0];
                *(ushort8v*)&As[rb + 32 + sg0*8] = va[i][1];
            }
            {
                int rb = sr*64;
                *(ushort8v*)&Xs[0][rb +  0 + sg0*8] = vw0[0];
                *(ushort8v*)&Xs[0][rb + 32 + sg0*8] = vw0[1];
                *(ushort8v*)&Xs[1][rb +  0 + sg0*8] = vw2[0];
                *(ushort8v*)&Xs[1][rb + 32 + sg0*8] = vw2[1];
            }
            if (t + 1 < nsteps) loadk((t+1)*64);
            __syncthreads();
            #pragma unroll
            for (int kk = 0; kk < 64; kk += 32) {
                bf16x8 a[4], b1[2], b2[2];
                #pragma unroll
                for (int s = 0; s < 4; ++s) {
                    int r = wr*64 + s*16 + fr;
                    a[s] = *(const bf16x8*)&As[r*64 + kk + gsl];
                }
                #pragma unroll
                for (int u = 0; u < 2; ++u) {
                    int r = wc*32 + u*16 + fr;
                    b1[u] = *(const bf16x8*)&Xs[0][r*64 + kk + gsl];
                    b2[u] = *(const bf16x8*)&Xs[1][r*64 + kk + gsl];
                }
                #pragma unroll
                for (int s = 0; s < 4; ++s)
                    #pragma unroll
                    for (int u = 0; u < 2; ++u) {
                        acc1[s][u] = MFMA(a[s], b1[u], acc1[s][u]);
                        acc2[s][u] = MFMA(a[s], b2[u], acc2[s][u]);
                    }
            }
        }
        #pragma unroll
        for (int s = 0; s < 4; ++s) {
            int rb = row0 + wr*64 + s*16 + fg*4;
            #pragma unroll
            for (int u = 0; u < 2; ++u) {
                int c = col0 + wc*32 + u*16 + fr;
                #pragma unroll
                for (int j = 0; j < 4; ++j) {
                    float gg = acc1[s][u][j] * gelu_f(acc2[s][u][j]);
                    Oh[(size_t)(rb+j)*ldo + c] = f2b(gg);
                }
            }
        }
    }
}

// ------------- batched pk GEMM (2-product, precomputed once): P12[z] = ptp @ Wkv[z]^T -------------
__global__ __launch_bounds__(256)
void pk_mm(const ushort* __restrict__ A,
           const ushort* __restrict__ Wh_, const ushort* __restrict__ Wl_,
           float* __restrict__ P12)
{
    __shared__ ushort Ah[64][72], Wh[64][72], Wl[64][72];
    int tid = threadIdx.x;
    int z = blockIdx.z, blk = z >> 1, half = z & 1;
    int row0 = blockIdx.y*64, col0 = blockIdx.x*64;
    int srow = tid >> 3, sseg = (tid & 7) * 8;
    int wid = tid >> 6, lane = tid & 63;
    int wr = wid >> 1, wc = wid & 1;
    int fr = lane & 15, fg = lane >> 4;
    const ushort* Wbh = Wh_ + (size_t)blk*816*384 + half*192;
    const ushort* Wbl = Wl_ + (size_t)blk*816*384 + half*192;
    float* C = P12 + (size_t)z*128*816;
    f32x4 acc[2][2] = {};
    for (int k0 = 0; k0 < 192; k0 += 64) {
        ushort8v va[2], vc[2], vd[2];
        #pragma unroll
        for (int p = 0; p < 2; ++p) {
            int r = p*32 + srow;
            int wrow = col0 + r; if (wrow >= 816) wrow = 815;
            int gk = k0 + sseg;
            va[p] = *(const ushort8v*)(A + (size_t)(row0 + r)*192 + gk);
            vc[p] = *(const ushort8v*)(Wbh + (size_t)wrow*384 + gk);
            vd[p] = *(const ushort8v*)(Wbl + (size_t)wrow*384 + gk);
        }
        __syncthreads();
        #pragma unroll
        for (int p = 0; p < 2; ++p) {
            int r = p*32 + srow;
            *(ushort8v*)&Ah[r][sseg] = va[p];
            *(ushort8v*)&Wh[r][sseg] = vc[p];
            *(ushort8v*)&Wl[r][sseg] = vd[p];
        }
        __syncthreads();
        #pragma unroll
        for (int kk = 0; kk < 64; kk += 32) {
            bf16x8 a[2], b_h[2], b_l[2];
            #pragma unroll
            for (int s = 0; s < 2; ++s) {
                a[s]   = *(const bf16x8*)&Ah[wr*32 + s*16 + fr][kk + fg*8];
                b_h[s] = *(const bf16x8*)&Wh[wc*32 + s*16 + fr][kk + fg*8];
                b_l[s] = *(const bf16x8*)&Wl[wc*32 + s*16 + fr][kk + fg*8];
            }
            #pragma unroll
            for (int s = 0; s < 2; ++s)
                #pragma unroll
                for (int u = 0; u < 2; ++u)
                    acc[s][u] = MFMA(a[s], b_h[u], acc[s][u]);
            #pragma unroll
            for (int s = 0; s < 2; ++s)
                #pragma unroll
                for (int u = 0; u < 2; ++u)
                    acc[s][u] = MFMA(a[s], b_l[u], acc[s][u]);
        }
        __syncthreads();
    }
    #pragma unroll
    for (int s = 0; s < 2; ++s) {
        int r = row0 + wr*32 + s*16 + fg*4;
        #pragma unroll
        for (int u = 0; u < 2; ++u) {
            int c = col0 + wc*32 + u*16 + fr;
            if (c < 816) {
                #pragma unroll
                for (int j = 0; j < 4; ++j)
                    C[(size_t)(r+j)*816 + c] = acc[s][u][j];
            }
        }
    }
}

// ------------- MFMA batched PV v2: 64x128 block, wave 64x32, T14 pipelined -------------
__global__ __launch_bounds__(256)
void pv2(const ushort* __restrict__ P, int ldp, long sP,
         const ushort* __restrict__ V, int ldv, long sV,
         ushort* __restrict__ Oh, int ldo, long sO,
         int Mrows, int K, int Kv)
{
    __shared__ ushort Ps[64][40];
    __shared__ ushort Vs[128*32];
    int L = blockIdx.x + gridDim.x*(blockIdx.y + gridDim.y*blockIdx.z);
    int gz = gridDim.z;
    int zz = L % gz;
    int rest = L / gz;
    int bx = rest % gridDim.x;
    int byy = rest / gridDim.x;
    const ushort* Pb = P + (size_t)zz * sP;
    const ushort* Vb = V + (size_t)zz * sV;
    ushort* Ohb = Oh + (size_t)zz * sO;
    int tid = threadIdx.x;
    int row0 = byy*64, col0 = bx*128;
    int wid = tid >> 6, lane = tid & 63;
    int fr = lane & 15, fg = lane >> 4;
    int prow = tid >> 2, pseg = (tid & 3) * 8;
    int vk = tid & 31, vcb = (tid >> 5) * 8;

    ushort8v pv_, vv[2];
    auto loadk = [&](int k0) {
        pv_ = (ushort8v){0,0,0,0,0,0,0,0};
        int grow = row0 + prow;
        if (grow < Mrows)
            pv_ = *(const ushort8v*)(Pb + (size_t)grow*ldp + k0 + pseg);
        vv[0] = (ushort8v){0,0,0,0,0,0,0,0};
        vv[1] = (ushort8v){0,0,0,0,0,0,0,0};
        int gk = k0 + vk;
        if (gk < Kv) {
            #pragma unroll
            for (int i = 0; i < 2; ++i)
                vv[i] = *(const ushort8v*)(Vb + (size_t)gk*ldv + col0 + vcb + i*64);
        }
    };

    f32x4 acc[4][2] = {};
    loadk(0);
    for (int k0 = 0; k0 < K; k0 += 32) {
        __syncthreads();
        *(ushort8v*)&Ps[prow][pseg] = pv_;
        #pragma unroll
        for (int i = 0; i < 2; ++i) {
            #pragma unroll
            for (int e = 0; e < 8; ++e) {
                int c = vcb + i*64 + e;
                Vs[c*32 + (vk & 7) + 8*((vk >> 3) ^ ((c >> 3) & 3))] = vv[i][e];
            }
        }
        if (k0 + 32 < K) loadk(k0 + 32);
        __syncthreads();
        bf16x8 a[4], b[2];
        #pragma unroll
        for (int s = 0; s < 4; ++s)
            a[s] = *(const bf16x8*)&Ps[s*16 + fr][fg*8];
        #pragma unroll
        for (int u = 0; u < 2; ++u) {
            int c = wid*32 + u*16 + fr;
            b[u] = *(const bf16x8*)&Vs[c*32 + 8*(fg ^ ((c >> 3) & 3))];
        }
        #pragma unroll
        for (int s = 0; s < 4; ++s)
            #pragma unroll
            for (int u = 0; u < 2; ++u)
                acc[s][u] = MFMA(a[s], b[u], acc[s][u]);
    }
    #pragma unroll
    for (int s = 0; s < 4; ++s) {
        int rbase = row0 + s*16 + fg*4;
        #pragma unroll
        for (int u = 0; u < 2; ++u) {
            int c = col0 + wid*32 + u*16 + fr;
            #pragma unroll
            for (int j = 0; j < 4; ++j) {
                int r = rbase + j;
                if (r < Mrows)
                    Ohb[(size_t)r*ldo + c] = f2b(acc[s][u][j]);
            }
        }
    }
}

// ------------- MFMA attention scores + softmax -> normalized P (bf16) -------------
template<int NK, int CAUSAL>
__global__ __launch_bounds__(256)
void attn_score_mfma(const float* __restrict__ Q, int ldq, long sQ,
                     const float* __restrict__ Kf, int ldk, int koff, long sK,
                     ushort* __restrict__ P,
                     const float* __restrict__ bm, int blk, int Kv)
{
    constexpr int NKF = NK / 16;
    __shared__ ushort Qs[64*72];
    __shared__ ushort Ks[NK*72];
    int slab = blockIdx.x;
    int zz = blockIdx.y;
    int row0 = slab*64;
    int tid = threadIdx.x;
    int wv = tid >> 6, lane = tid & 63;
    int fr = lane & 15, fg = lane >> 4;

    const float scale = 0.14433756729740643f;
    float sp = 0.f;
    if (CAUSAL) { float bmv = bm[blk]; sp = (bmv > 20.f) ? bmv : log1pf(expf(bmv)); }

    const float* Qb = Q + (size_t)zz * sQ;
    for (int idx = tid; idx < 64*64; idx += 256) {
        int r = idx >> 6, c = idx & 63;
        int grow = row0 + r; if (grow >= S_) grow = S_ - 1;
        ushort v = 0;
        if (c < 48) v = f2b(Qb[(size_t)grow*ldq + c]);
        Qs[r*72 + c] = v;
    }
    const float* Kb = Kf + (size_t)zz*sK + koff;
    for (int idx = tid; idx < NK*64; idx += 256) {
        int j = idx >> 6, c = idx & 63;
        ushort v = 0;
        if (c < 48 && j < Kv) v = f2b(Kb[(size_t)j*ldk + c]);
        Ks[j*72 + c] = v;
    }
    __syncthreads();

    f32x4 sacc[NKF];
    #pragma unroll
    for (int kf = 0; kf < NKF; ++kf) sacc[kf] = (f32x4){0.f,0.f,0.f,0.f};
    bf16x8 aq0 = *(const bf16x8*)&Qs[(wv*16 + fr)*72 +  0 + fg*8];
    bf16x8 aq1 = *(const bf16x8*)&Qs[(wv*16 + fr)*72 + 32 + fg*8];
    #pragma unroll
    for (int kf = 0; kf < NKF; ++kf) {
        bf16x8 bk0 = *(const bf16x8*)&Ks[(kf*16 + fr)*72 +  0 + fg*8];
        bf16x8 bk1 = *(const bf16x8*)&Ks[(kf*16 + fr)*72 + 32 + fg*8];
        sacc[kf] = MFMA(aq0, bk0, sacc[kf]);
        sacc[kf] = MFMA(aq1, bk1, sacc[kf]);
    }
    #pragma unroll
    for (int j = 0; j < 4; ++j) {
        int i = row0 + wv*16 + fg*4 + j;
        float m = -1e30f;
        #pragma unroll
        for (int kf = 0; kf < NKF; ++kf) {
            int key = kf*16 + fr;
            float s = sacc[kf][j] * scale;
            if (CAUSAL) s = (key <= i) ? (s + sp*(float)(key - i)) : -1e30f;
            sacc[kf][j] = s;
            m = fmaxf(m, s);
        }
        #pragma unroll
        for (int off = 1; off < 16; off <<= 1) m = fmaxf(m, __shfl_xor(m, off));
        float sum = 0.f;
        #pragma unroll
        for (int kf = 0; kf < NKF; ++kf) {
            float p = __expf(sacc[kf][j] - m);
            sacc[kf][j] = p;
            sum += p;
        }
        #pragma unroll
        for (int off = 1; off < 16; off <<= 1) sum += __shfl_xor(sum, off);
        float inv = 1.f / sum;
        if (i < S_) {
            ushort* prow = P + ((size_t)(zz*S_) + i)*NK;
            #pragma unroll
            for (int kf = 0; kf < NKF; ++kf)
                prow[kf*16 + fr] = f2b(sacc[kf][j] * inv);
        }
    }
}

// ------------- gather pk rows -> k2 (fp32), geglu'd values gv (bf16) -------------
__global__ __launch_bounds__(256)
void pk_gather(const int* __restrict__ pts, const float* __restrict__ P12, int blk,
               float* __restrict__ k2, ushort* __restrict__ gv)
{
    int pair = blockIdx.x*4 + (threadIdx.x >> 6);
    int lane = threadIdx.x & 63;
    const float* P1 = P12 + (size_t)(blk*2 + 0)*128*816;
    const float* P2 = P12 + (size_t)(blk*2 + 1)*128*816;
    int t0 = pts[2*pair], t1 = pts[2*pair+1];
    const float* a = P1 + (size_t)t0*816;
    const float* c = P2 + (size_t)t1*816;
    if (lane < QK_) k2[(size_t)pair*QK_ + lane] = a[lane] + c[lane];
    #pragma unroll
    for (int t = 0; t < 6; ++t) {
        int i = lane + 64*t;
        float lin = a[48 + i] + c[48 + i];
        float pre = a[432 + i] + c[432 + i];
        gv[(size_t)pair*D_ + i] = f2b(lin * gelu_f(pre));
    }
}

// all layers at once: blockIdx.y = layer
__global__ __launch_bounds__(256)
void pk_gather_all(const int* __restrict__ pts, const float* __restrict__ P12,
                   float* __restrict__ k2, ushort* __restrict__ gv)
{
    int pair = blockIdx.x*4 + (threadIdx.x >> 6);
    int lane = threadIdx.x & 63;
    int blk = blockIdx.y;
    const float* P1 = P12 + (size_t)(blk*2 + 0)*128*816;
    const float* P2 = P12 + (size_t)(blk*2 + 1)*128*816;
    float* k2b = k2 + (size_t)blk*B_*NPTS_*QK_;
    ushort* gvb = gv + (size_t)blk*B_*NPTS_*D_;
    int t0 = pts[2*pair], t1 = pts[2*pair+1];
    const float* a = P1 + (size_t)t0*816;
    const float* c = P2 + (size_t)t1*816;
    if (lane < QK_) k2b[(size_t)pair*QK_ + lane] = a[lane] + c[lane];
    #pragma unroll
    for (int t = 0; t < 6; ++t) {
        int i = lane + 64*t;
        float lin = a[48 + i] + c[48 + i];
        float pre = a[432 + i] + c[432 + i];
        gvb[(size_t)pair*D_ + i] = f2b(lin * gelu_f(pre));
    }
}

extern "C" void kernel_launch(void* const* d_in, const int* in_sizes, int n_in,
                              void* d_out, int out_size, void* d_ws, size_t ws_size,
                              hipStream_t stream)
{
    const int*   qtok  = (const int*)d_in[0];
    const int*   pts   = (const int*)d_in[1];
    const float* emb   = (const float*)d_in[2];
    const float* ptemb = (const float*)d_in[3];
    const float* normw = (const float*)d_in[4];
    const float* outw  = (const float*)d_in[5];
    const float* ln1   = (const float*)d_in[6];
    const float* expand= (const float*)d_in[7];
    const float* proj1 = (const float*)d_in[8];
    const float* bm    = (const float*)d_in[9];
    const float* ln2   = (const float*)d_in[10];
    const float* Wq    = (const float*)d_in[11];
    const float* Wkv   = (const float*)d_in[12];
    const float* proj2 = (const float*)d_in[13];
    float* out = (float*)d_out;

    char* base = (char*)d_ws;
    size_t off = 0;
    auto alloc = [&](size_t bytes){ void* p = base + off; off += (bytes + 255) & ~(size_t)255; return p; };
    float*  h     = (float*) alloc((size_t)M_*D_*4);
    ushort* nh    = (ushort*)alloc((size_t)M_*D_*2);
    float*  qk1   = (float*) alloc((size_t)M_*96*4);     // qr2 aliases
    ushort* gegl  = (ushort*)alloc((size_t)M_*E_*2);     // gloc aliases
    ushort* atb   = (ushort*)alloc((size_t)M_*D_*2);
    ushort* Pbuf  = (ushort*)alloc((size_t)M_*256*2);
    float*  P12   = (float*) alloc((size_t)16*128*816*4);
    ushort* wkvh  = (ushort*)alloc((size_t)NB_*816*384*2);
    ushort* wkvl  = (ushort*)alloc((size_t)NB_*816*384*2);
    ushort* ptp   = (ushort*)alloc((size_t)128*192*2);
    ushort* obh   = (ushort*)alloc((size_t)NTOK_*D_*2);
    ushort* obl   = (ushort*)alloc((size_t)NTOK_*D_*2);

    // weight buffer (hi only): all 8 layers if workspace allows, else single-layer
    size_t rem = (ws_size > off) ? (ws_size - off) : 0;
    bool fits8 = rem >= ((size_t)NB_ * WTOT * 2
                         + (size_t)B_*NPTS_*D_*2 + (size_t)B_*NPTS_*QK_*4 + 4096);
    int nlay = fits8 ? NB_ : 1;
    ushort* wbh = (ushort*)alloc((size_t)nlay*WTOT*2);
    size_t wstride = fits8 ? (size_t)WTOT : 0;

    // pk-gather buffers: all 8 layers if workspace allows (hoist), else per-layer
    size_t gv_l = (size_t)B_*NPTS_*D_;   // elements (ushort)
    size_t k2_l = (size_t)B_*NPTS_*QK_;  // elements (float)
    size_t rem2 = (ws_size > off) ? (ws_size - off) : 0;
    bool fitsPK = rem2 >= ((size_t)NB_*gv_l*2 + (size_t)NB_*k2_l*4 + 4096);
    int play = fitsPK ? NB_ : 1;
    ushort* gvB = (ushort*)alloc((size_t)play*gv_l*2);
    float*  k2B = (float*) alloc((size_t)play*k2_l*4);
    size_t gvs = fitsPK ? gv_l : 0;
    size_t k2s = fitsPK ? k2_l : 0;

    float*  qr2   = qk1;
    ushort* gloc  = gegl;

    const size_t oWE = 0;
    const size_t oP1 = WE_SZ;
    const size_t oWQ = WE_SZ + P1_SZ;
    const size_t oP2 = WE_SZ + P1_SZ + WQ_SZ;

    x_init<<<M_/4, 256, 0, stream>>>(qtok, emb, normw, h, M_);
    pconv<<<(128*192 + 255)/256, 256, 0, stream>>>(ptemb, ptp);
    wconv1<<<(NB_*816*384 + 255)/256, 256, 0, stream>>>(Wkv, NB_*816*384, wkvh, wkvl);
    pk_mm<<<dim3(13, 2, 16), 256, 0, stream>>>(ptp, wkvh, wkvl, P12);
    if (fits8)
        wconv_all_hi<<<dim3((WTOT+255)/256, NB_), 256, 0, stream>>>(
            expand, proj1, Wq, proj2, wbh);
    if (fitsPK)
        pk_gather_all<<<dim3(B_*NPTS_/4, NB_), 256, 0, stream>>>(pts, P12, k2B, gvB);

    for (int blk = 0; blk < NB_; ++blk) {
        if (!fits8)
            wconv_hi<<<(WTOT+255)/256, 256, 0, stream>>>(
                expand + (size_t)blk*WE_SZ, proj1 + (size_t)blk*P1_SZ,
                Wq + (size_t)blk*WQ_SZ, proj2 + (size_t)blk*P2_SZ, wbh);
        const ushort* Lh = wbh + wstride*blk;
        ushort* gv = gvB + gvs*blk;
        float*  k2 = k2B + k2s*blk;

        ln_rows<<<M_/4, 256, 0, stream>>>(h, ln1 + blk*D_, nh, M_);
        // fused: qk (N=96 -> 2 tiles) + geglu768 (12 tiles)
        mm_fused2<<<dim3(14, M_/128), 256, 0, stream>>>(nh, D_,
            Lh + oWE, 96, 2, qk1, 96,
            Lh + oWE + (size_t)96*D_, Lh + oWE + (size_t)864*D_,
            gegl, E_, D_);
        // MFMA scores + softmax (causal + linear bias), keys padded 100->128
        attn_score_mfma<128,1><<<dim3(2, B_), 256, 0, stream>>>(
            qk1, 96, (long)S_*96,
            qk1, 96, 48, (long)S_*96,
            Pbuf, bm, blk, S_);
        pv2<<<dim3(3,2,B_), 256, 0, stream>>>(Pbuf, 128, (long)S_*128,
            gegl + LOCAL_, E_, (long)S_*E_,
            atb, D_, (long)S_*D_, S_, 128, S_);
        // h += [geglu_local | attn] @ W_p1^T
        mm_bt2<<<dim3(6, M_/128), 256, 0, stream>>>(gegl, E_, D_, atb, D_,
            Lh + oP1, h, D_, D_, E_, 1);

        ln_rows<<<M_/4, 256, 0, stream>>>(h, ln2 + blk*D_, nh, M_);
        // fused: qr2 (N=48 -> 1 tile) + geglu384 (6 tiles)
        mm_fused2<<<dim3(7, M_/128), 256, 0, stream>>>(nh, D_,
            Lh + oWQ, 48, 1, qr2, 48,
            Lh + oWQ + (size_t)48*D_, Lh + oWQ + (size_t)432*D_,
            gloc, D_, D_);
        // pk path (P12 precomputed; gather hoisted if it fits)
        if (!fitsPK)
            pk_gather<<<B_*NPTS_/4, 256, 0, stream>>>(pts, P12, blk, k2, gv);
        // MFMA scores + softmax (no mask), 256 keys
        attn_score_mfma<256,0><<<dim3(2, B_), 256, 0, stream>>>(
            qr2, 48, (long)S_*48,
            k2, 48, 0, (long)NPTS_*48,
            Pbuf, bm, blk, NPTS_);
        pv2<<<dim3(3,2,B_), 256, 0, stream>>>(Pbuf, 256, (long)S_*256,
            gv, D_, (long)NPTS_*D_,
            atb, D_, (long)S_*D_, S_, 256, 256);
        // h += [g_local | attn2] @ W_p2^T
        mm_bt2<<<dim3(6, M_/128), 256, 0, stream>>>(gloc, D_, D_, atb, D_,
            Lh + oP2, h, D_, D_, E_, 1);
    }

    ln_rows<<<M_/4, 256, 0, stream>>>(h, normw, nh, M_);
    wconv1<<<(NTOK_*D_ + 255)/256, 256, 0, stream>>>(outw, NTOK_*D_, obh, obl);
    mm_bt64<<<dim3(2, M_/64), 256, 0, stream>>>(nh, D_, D_, nh, D_,
        obh, obl, out, NTOK_, NTOK_, D_, 0);
}